// Round 1
// baseline (7908.083 us; speedup 1.0000x reference)
//
#include <hip/hip_runtime.h>
#include <hip/hip_bf16.h>
#include <math.h>

#define BB 64
#define NA 32
#define NTOT (BB*NA)      // 2048
#define HID 600
#define NG 50
#define NL 6
#define NEDGE (BB*NA*NA)  // 65536
#define JH 16             // j's per edge_msg block (half of 32)

// ShiftedSoftplus: log1p(exp(x)) - log(2) == log(0.5 + 0.5*exp(x))
__device__ __forceinline__ float sspf(float x) {
    return (x > 15.f) ? (x - 0.69314718056f)
                      : __logf(0.5f + 0.5f * __expf(x));
}

// ---------------------------------------------------------------------------
// Edge prep: rbf[NEDGE][NG], cosw[NEDGE]
// ---------------------------------------------------------------------------
__global__ void prep_edges(const float* __restrict__ pos,
                           float* __restrict__ rbf, float* __restrict__ cw) {
    int e = blockIdx.x * blockDim.x + threadIdx.x;
    if (e >= NEDGE) return;
    int b  = e >> 10;
    int ij = e & 1023;
    int i = ij >> 5, j = ij & 31;
    int ai = b*NA + i, aj = b*NA + j;
    float dx = pos[ai*3+0] - pos[aj*3+0];
    float dy = pos[ai*3+1] - pos[aj*3+1];
    float dz = pos[ai*3+2] - pos[aj*3+2];
    float sq = dx*dx + dy*dy + dz*dz;
    float d  = sqrtf(sq > 0.f ? sq : 1.f);
    float m  = ((sq <= 100.f) && (i != j)) ? 1.f : 0.f;
    cw[e] = 0.5f * (cosf(d * 0.31415926535f) + 1.f) * m;
    const float step  = 10.f / 49.f;
    const float coeff = -0.5f / (step*step);
    #pragma unroll
    for (int g = 0; g < NG; g++) {
        float t = d - step * (float)g;
        rbf[(size_t)e*NG + g] = __expf(coeff * t * t);
    }
}

// ---------------------------------------------------------------------------
// h0 = emb[z]
// ---------------------------------------------------------------------------
__global__ void gather_h(const int* __restrict__ z, const float* __restrict__ emb,
                         float* __restrict__ h) {
    int n = blockIdx.x;
    int zi = z[n];
    for (int f = threadIdx.x; f < HID; f += blockDim.x)
        h[(size_t)n*HID + f] = emb[(size_t)zi*HID + f];
}

// ---------------------------------------------------------------------------
// Fused edge filter + message:
//   t[j][k]    = ssp(rbf[e]@w1 + b1)                (LDS)
//   W[j][f]    = t[j]@w2[:,f] + b2[f]
//   mpart[f]  += cosw[e] * xj[atom_j][f] * W[j][f]  (sum over 16 j's)
// block = (bi = b*32+i, jh); 128 threads
// ---------------------------------------------------------------------------
__global__ __launch_bounds__(128) void edge_msg(
    const float* __restrict__ rbf, const float* __restrict__ cw,
    const float* __restrict__ xj, const float* __restrict__ w1,
    const float* __restrict__ b1, const float* __restrict__ w2,
    const float* __restrict__ b2, float* __restrict__ mpart)
{
    const int bi = blockIdx.x;      // 0..2047
    const int jh = blockIdx.y;      // 0..1
    const int b  = bi >> 5;
    const int j0 = jh * JH;
    const int ebase = bi * NA + j0; // edge index base
    const int tid = threadIdx.x;

    __shared__ float t_s[JH][HID];      // 38.4 KB
    __shared__ float rbf_s[JH][NG];
    __shared__ float cw_s[JH];

    for (int idx = tid; idx < JH*NG; idx += 128) {
        int j = idx / NG, c = idx - j*NG;
        rbf_s[j][c] = rbf[(size_t)(ebase + j)*NG + c];
    }
    if (tid < JH) cw_s[tid] = cw[ebase + tid];
    __syncthreads();

    // ---- phase 1: filter MLP layer 1 + ssp ----
    for (int j = 0; j < JH; j++) {
        float rr[NG];
        #pragma unroll
        for (int c = 0; c < NG; c++) rr[c] = rbf_s[j][c];
        for (int k = tid; k < HID; k += 128) {
            float acc = b1[k];
            #pragma unroll
            for (int c = 0; c < NG; c++)
                acc = fmaf(rr[c], w1[c*HID + k], acc);
            t_s[j][k] = sspf(acc);
        }
    }
    __syncthreads();

    // ---- phase 2: t @ w2, register-blocked 16j x 5f per thread ----
    float acc[JH][5];
    #pragma unroll
    for (int j = 0; j < JH; j++)
        #pragma unroll
        for (int s = 0; s < 5; s++) acc[j][s] = 0.f;

    int fidx[5];
    #pragma unroll
    for (int s = 0; s < 5; s++) {
        int f = tid + 128*s;
        fidx[s] = (f < HID) ? f : (HID-1);   // clamp; garbage lanes never stored
    }

    for (int k = 0; k < HID; k += 4) {
        float wq[4][5];
        #pragma unroll
        for (int q = 0; q < 4; q++)
            #pragma unroll
            for (int s = 0; s < 5; s++)
                wq[q][s] = w2[(size_t)(k+q)*HID + fidx[s]];
        #pragma unroll
        for (int j = 0; j < JH; j++) {
            float4 t4 = *(const float4*)&t_s[j][k];   // wave-uniform broadcast
            #pragma unroll
            for (int s = 0; s < 5; s++) {
                acc[j][s] = fmaf(t4.x, wq[0][s], acc[j][s]);
                acc[j][s] = fmaf(t4.y, wq[1][s], acc[j][s]);
                acc[j][s] = fmaf(t4.z, wq[2][s], acc[j][s]);
                acc[j][s] = fmaf(t4.w, wq[3][s], acc[j][s]);
            }
        }
    }

    // ---- epilogue: + b2, * cosw * xj, reduce over j ----
    #pragma unroll
    for (int s = 0; s < 5; s++) {
        int f = tid + 128*s;
        if (f < HID) {
            float bb2 = b2[f];
            float msum = 0.f;
            #pragma unroll
            for (int j = 0; j < JH; j++) {
                float Wv = acc[j][s] + bb2;
                msum += cw_s[j] * xj[(size_t)(b*NA + j0 + j)*HID + f] * Wv;
            }
            mpart[(size_t)jh*NTOT*HID + (size_t)bi*HID + f] = msum;
        }
    }
}

// ---------------------------------------------------------------------------
// Generic fp32 GEMM: C = [res +] act( (A [+A2]) @ W + bias )
// 64x64 tile, 256 threads, 4x4 per thread. Requires M % 64 == 0.
// ---------------------------------------------------------------------------
template<int ACT, int ASUM, int RES>
__global__ __launch_bounds__(256) void gemm64(
    const float* __restrict__ A, const float* __restrict__ A2,
    const float* __restrict__ W, const float* __restrict__ bias,
    const float* __restrict__ res, float* __restrict__ C,
    int M, int K, int Nn)
{
    __shared__ float As[64][17];
    __shared__ float Ws[16][64];
    const int tid = threadIdx.x;
    const int rb = blockIdx.x * 64, cb = blockIdx.y * 64;
    const int tx = tid & 15, ty = tid >> 4;

    float accv[4][4] = {};
    const int ar = tid >> 2;          // 0..63
    const int ak = (tid & 3) * 4;     // 0,4,8,12
    const int wk = tid >> 4;          // 0..15
    const int wc = (tid & 15) * 4;    // 0..60

    for (int k0 = 0; k0 < K; k0 += 16) {
        float4 av = make_float4(0.f,0.f,0.f,0.f);
        if (k0 + ak < K) {
            av = *(const float4*)&A[(size_t)(rb+ar)*K + k0 + ak];
            if (ASUM) {
                float4 a2 = *(const float4*)&A2[(size_t)(rb+ar)*K + k0 + ak];
                av.x += a2.x; av.y += a2.y; av.z += a2.z; av.w += a2.w;
            }
        }
        float4 wv = make_float4(0.f,0.f,0.f,0.f);
        if (k0 + wk < K && cb + wc < Nn)
            wv = *(const float4*)&W[(size_t)(k0+wk)*Nn + cb + wc];
        __syncthreads();
        As[ar][ak+0]=av.x; As[ar][ak+1]=av.y; As[ar][ak+2]=av.z; As[ar][ak+3]=av.w;
        *(float4*)&Ws[wk][wc] = wv;
        __syncthreads();
        #pragma unroll
        for (int kk = 0; kk < 16; kk++) {
            float4 wrow = *(const float4*)&Ws[kk][tx*4];
            float wr[4] = {wrow.x, wrow.y, wrow.z, wrow.w};
            float aa[4] = {As[ty*4+0][kk], As[ty*4+1][kk],
                           As[ty*4+2][kk], As[ty*4+3][kk]};
            #pragma unroll
            for (int u = 0; u < 4; u++)
                #pragma unroll
                for (int v = 0; v < 4; v++)
                    accv[u][v] = fmaf(aa[u], wr[v], accv[u][v]);
        }
    }

    #pragma unroll
    for (int u = 0; u < 4; u++) {
        int r = rb + ty*4 + u;
        #pragma unroll
        for (int v = 0; v < 4; v++) {
            int c = cb + tx*4 + v;
            if (c < Nn) {
                float x = accv[u][v];
                if (bias) x += bias[c];
                if (ACT == 1) x = sspf(x);
                if (RES) x += res[(size_t)r*Nn + c];
                C[(size_t)r*Nn + c] = x;
            }
        }
    }
}

// ---------------------------------------------------------------------------
// pooled[b] = mean over atoms of h
// ---------------------------------------------------------------------------
__global__ void pool_mean(const float* __restrict__ h, float* __restrict__ pooled) {
    int b = blockIdx.x;
    for (int f = threadIdx.x; f < HID; f += blockDim.x) {
        float s = 0.f;
        #pragma unroll
        for (int i = 0; i < NA; i++) s += h[(size_t)(b*NA+i)*HID + f];
        pooled[(size_t)b*HID + f] = s * (1.f/NA);
    }
}

// ---------------------------------------------------------------------------
extern "C" void kernel_launch(void* const* d_in, const int* in_sizes, int n_in,
                              void* d_out, int out_size, void* d_ws, size_t ws_size,
                              hipStream_t stream)
{
    const int*   z    = (const int*)  d_in[0];
    const float* pos  = (const float*)d_in[1];
    const float* emb  = (const float*)d_in[3];
    const float* mw1  = (const float*)d_in[4];
    const float* mb1  = (const float*)d_in[5];
    const float* mw2  = (const float*)d_in[6];
    const float* mb2  = (const float*)d_in[7];
    const float* l1w  = (const float*)d_in[8];
    const float* l2w  = (const float*)d_in[9];
    const float* l2b  = (const float*)d_in[10];
    const float* lw   = (const float*)d_in[11];
    const float* lb   = (const float*)d_in[12];
    const float* pw   = (const float*)d_in[13];
    const float* pb   = (const float*)d_in[14];

    float* wsf    = (float*)d_ws;
    float* rbf    = wsf;                                  // 65536*50
    float* cw     = rbf + (size_t)NEDGE*NG;               // 65536
    float* h      = cw  + NEDGE;                          // 2048*600
    float* xj     = h   + (size_t)NTOT*HID;               // 2048*600
    float* mp     = xj  + (size_t)NTOT*HID;               // 2 * 2048*600
    float* v1     = mp  + (size_t)2*NTOT*HID;             // 2048*600
    float* pooled = v1  + (size_t)NTOT*HID;               // 64*600
    // total ~38.1 MB of d_ws

    prep_edges<<<NEDGE/256, 256, 0, stream>>>(pos, rbf, cw);
    gather_h<<<NTOT, 256, 0, stream>>>(z, emb, h);

    dim3 gg(NTOT/64, (HID+63)/64);
    for (int l = 0; l < NL; l++) {
        const float* w1l  = mw1 + (size_t)l*NG*HID;
        const float* b1l  = mb1 + (size_t)l*HID;
        const float* w2l  = mw2 + (size_t)l*HID*HID;
        const float* b2l  = mb2 + (size_t)l*HID;
        const float* l1wl = l1w + (size_t)l*HID*HID;
        const float* l2wl = l2w + (size_t)l*HID*HID;
        const float* l2bl = l2b + (size_t)l*HID;
        const float* lwl  = lw  + (size_t)l*HID*HID;
        const float* lbl  = lb  + (size_t)l*HID;

        // xj = h @ lin1_w (no bias)
        gemm64<0,0,0><<<gg, 256, 0, stream>>>(h, nullptr, l1wl, nullptr, nullptr,
                                              xj, NTOT, HID, HID);
        // fused filter-net + message partials
        edge_msg<<<dim3(NTOT,2), 128, 0, stream>>>(rbf, cw, xj, w1l, b1l, w2l, b2l, mp);
        // v1 = ssp((mp0+mp1) @ lin2_w + lin2_b)
        gemm64<1,1,0><<<gg, 256, 0, stream>>>(mp, mp + (size_t)NTOT*HID, l2wl, l2bl,
                                              nullptr, v1, NTOT, HID, HID);
        // h = h + v1 @ lin_w + lin_b
        gemm64<0,0,1><<<gg, 256, 0, stream>>>(v1, nullptr, lwl, lbl, h,
                                              h, NTOT, HID, HID);
    }

    pool_mean<<<BB, 256, 0, stream>>>(h, pooled);
    gemm64<0,0,0><<<dim3(1, (HID+63)/64), 256, 0, stream>>>(pooled, nullptr, pw, pb,
                                                            nullptr, (float*)d_out,
                                                            BB, HID, HID);
}

// Round 2
// 2545.903 us; speedup vs baseline: 3.1062x; 3.1062x over previous
//
#include <hip/hip_runtime.h>
#include <hip/hip_bf16.h>
#include <math.h>

#define BB 64
#define NA 32
#define NTOT (BB*NA)      // 2048
#define HID 600
#define NG 50
#define NL 6
#define NEDGE (BB*NA*NA)  // 65536

typedef __attribute__((ext_vector_type(8))) short short8;   // 8 bf16 (4 VGPRs)
typedef __attribute__((ext_vector_type(4))) float f32x4;

__device__ __forceinline__ float sspf(float x) {
    return (x > 15.f) ? (x - 0.69314718056f)
                      : __logf(0.5f + 0.5f * __expf(x));
}

__device__ __forceinline__ unsigned short f2bf(float x) {
    union { float f; unsigned u; } v; v.f = x;
    unsigned r = v.u + 0x7FFF + ((v.u >> 16) & 1);   // RNE
    return (unsigned short)(r >> 16);
}

// ---------------------------------------------------------------------------
// Edge prep: rbf_bf[NEDGE][64] bf16 (k<50 valid, rest 0), cosw[NEDGE] fp32
// ---------------------------------------------------------------------------
__global__ void prep_edges(const float* __restrict__ pos,
                           unsigned short* __restrict__ rbf_bf,
                           float* __restrict__ cw) {
    int e = blockIdx.x * blockDim.x + threadIdx.x;
    if (e >= NEDGE) return;
    int b  = e >> 10;
    int ij = e & 1023;
    int i = ij >> 5, j = ij & 31;
    int ai = b*NA + i, aj = b*NA + j;
    float dx = pos[ai*3+0] - pos[aj*3+0];
    float dy = pos[ai*3+1] - pos[aj*3+1];
    float dz = pos[ai*3+2] - pos[aj*3+2];
    float sq = dx*dx + dy*dy + dz*dz;
    float d  = sqrtf(sq > 0.f ? sq : 1.f);
    float msk = ((sq <= 100.f) && (i != j)) ? 1.f : 0.f;
    cw[e] = 0.5f * (cosf(d * 0.31415926535f) + 1.f) * msk;
    const float step  = 10.f / 49.f;
    const float coeff = -0.5f / (step*step);
    #pragma unroll
    for (int g8 = 0; g8 < 8; g8++) {
        union { unsigned short us[8]; uint4 v; } u;
        #pragma unroll
        for (int q = 0; q < 8; q++) {
            int g = g8*8 + q;
            float t = d - step * (float)g;
            float val = (g < NG) ? __expf(coeff * t * t) : 0.f;
            u.us[q] = f2bf(val);
        }
        *(uint4*)(rbf_bf + (size_t)e*64 + g8*8) = u.v;
    }
}

// ---------------------------------------------------------------------------
// w1t[l][608][64] bf16 : w1t[f][k] = w1[l][k][f]  (zero-padded)
// ---------------------------------------------------------------------------
__global__ void transpose_w1(const float* __restrict__ w1,
                             unsigned short* __restrict__ w1t) {
    int idx = blockIdx.x;          // l*608 + fr
    int l = idx / 608, fr = idx - l*608;
    int k = threadIdx.x;           // 64 threads
    float v = (fr < HID && k < NG) ? w1[(size_t)l*NG*HID + (size_t)k*HID + fr] : 0.f;
    w1t[((size_t)l*608 + fr)*64 + k] = f2bf(v);
}

// ---------------------------------------------------------------------------
// w2t[l][640][608] bf16 : w2t[f][k] = w2[l][k][f]  (zero-padded)
// ---------------------------------------------------------------------------
__global__ void transpose_w2(const float* __restrict__ w2,
                             unsigned short* __restrict__ w2t) {
    int idx = blockIdx.x;          // l*640 + fr
    int l = idx / 640, fr = idx - l*640;
    for (int k = threadIdx.x; k < 608; k += 256) {
        float v = (fr < HID && k < HID) ? w2[(size_t)l*HID*HID + (size_t)k*HID + fr] : 0.f;
        w2t[((size_t)l*640 + fr)*608 + k] = f2bf(v);
    }
}

// ---------------------------------------------------------------------------
// h0 = emb[z]
// ---------------------------------------------------------------------------
__global__ void gather_h(const int* __restrict__ z, const float* __restrict__ emb,
                         float* __restrict__ h) {
    int n = blockIdx.x;
    int zi = z[n];
    for (int f = threadIdx.x; f < HID; f += blockDim.x)
        h[(size_t)n*HID + f] = emb[(size_t)zi*HID + f];
}

// ---------------------------------------------------------------------------
// Fused edge filter + message, bf16 MFMA.
// Block = 2 atoms (64 edges), 4 waves. Phase 1: t = ssp(rbf@w1+b1) -> LDS bf16
// (XOR-swizzled). Phase 2: W = t@w2t^T per 16-col f-tile (F=5 blocking),
// epilogue (+b2)*cosw*xj, reduce over j within fragments -> m[i][f] directly.
// ---------------------------------------------------------------------------
__global__ __launch_bounds__(256) void edge_mfma(
    const unsigned short* __restrict__ rbf_bf, const float* __restrict__ cw,
    const float* __restrict__ xj,
    const unsigned short* __restrict__ w1t, const float* __restrict__ b1,
    const unsigned short* __restrict__ w2t, const float* __restrict__ b2,
    float* __restrict__ m)
{
    __shared__ __align__(16) char t_smem[64*1216];   // t[64 edges][608 k] bf16, swizzled
    __shared__ float cw_s[64];

    const int tid  = threadIdx.x;
    const int wave = tid >> 6, lane = tid & 63;
    const int cl = lane & 15, gr = lane >> 4;
    const int bid = blockIdx.x;
    const int i0 = bid*2;                // first atom
    const int ebase = i0*32;             // first edge
    const int jbase = i0 & ~31;          // graph's first atom

    if (tid < 64) cw_s[tid] = cw[ebase + tid];

    // ---- phase 1: t = ssp(rbf @ w1 + b1), MFMA, K=64 (2 steps) ----
    short8 a1[4][2];
    #pragma unroll
    for (int fr = 0; fr < 4; fr++)
        #pragma unroll
        for (int ks = 0; ks < 2; ks++)
            a1[fr][ks] = *(const short8*)(rbf_bf + (size_t)(ebase + fr*16 + cl)*64 + ks*32 + gr*8);

    for (int ft = wave; ft < 38; ft += 4) {          // cols ft*16 .. ft*16+15 of t
        f32x4 acc[4] = {};
        #pragma unroll
        for (int ks = 0; ks < 2; ks++) {
            short8 bfr = *(const short8*)(w1t + (size_t)(ft*16 + cl)*64 + ks*32 + gr*8);
            #pragma unroll
            for (int fr = 0; fr < 4; fr++)
                acc[fr] = __builtin_amdgcn_mfma_f32_16x16x32_bf16(a1[fr][ks], bfr, acc[fr], 0, 0, 0);
        }
        int f = ft*16 + cl;
        float b1v = (f < HID) ? b1[f] : 0.f;         // f>=600 -> acc=0,b1=0 -> ssp(0)=0
        #pragma unroll
        for (int fr = 0; fr < 4; fr++)
            #pragma unroll
            for (int r = 0; r < 4; r++) {
                int row = fr*16 + gr*4 + r;
                float tv = sspf(acc[fr][r] + b1v);
                int byt = row*1216 + f*2;
                *(unsigned short*)(t_smem + (byt ^ ((row & 7) << 4))) = f2bf(tv);
            }
    }
    __syncthreads();

    // ---- phase 2: W = t @ w2t^T, fused message epilogue ----
    for (int grp = 0; grp < 2; grp++) {
        const int ft0 = wave*10 + grp*5;             // 5 f-tiles (80 cols) per group
        f32x4 acc[5][4] = {};
        for (int k0 = 0; k0 < 608; k0 += 32) {
            short8 a[4];
            #pragma unroll
            for (int fr = 0; fr < 4; fr++) {
                int row = fr*16 + cl;
                int byt = row*1216 + k0*2 + gr*16;
                a[fr] = *(const short8*)(t_smem + (byt ^ ((row & 7) << 4)));
            }
            #pragma unroll
            for (int s = 0; s < 5; s++) {
                short8 bfr = *(const short8*)(w2t + (size_t)((ft0 + s)*16 + cl)*608 + k0 + gr*8);
                #pragma unroll
                for (int fr = 0; fr < 4; fr++)
                    acc[s][fr] = __builtin_amdgcn_mfma_f32_16x16x32_bf16(a[fr], bfr, acc[s][fr], 0, 0, 0);
            }
        }
        #pragma unroll
        for (int s = 0; s < 5; s++) {
            int f = (ft0 + s)*16 + cl;
            if (f < HID) {                           // shfl partners share cl -> uniform
                float b2v = b2[f];
                float s0 = 0.f, s1 = 0.f;
                #pragma unroll
                for (int r = 0; r < 4; r++) {
                    float xa = xj[(size_t)(jbase + gr*4 + r)*HID + f];
                    float xb = xj[(size_t)(jbase + 16 + gr*4 + r)*HID + f];
                    s0 += cw_s[gr*4 + r]      * (acc[s][0][r] + b2v) * xa;
                    s0 += cw_s[16 + gr*4 + r] * (acc[s][1][r] + b2v) * xb;
                    s1 += cw_s[32 + gr*4 + r] * (acc[s][2][r] + b2v) * xa;
                    s1 += cw_s[48 + gr*4 + r] * (acc[s][3][r] + b2v) * xb;
                }
                s0 += __shfl_xor(s0, 16); s0 += __shfl_xor(s0, 32);
                s1 += __shfl_xor(s1, 16); s1 += __shfl_xor(s1, 32);
                if (gr == 0) {
                    m[(size_t)i0*HID + f]     = s0;
                    m[(size_t)(i0+1)*HID + f] = s1;
                }
            }
        }
    }
}

// ---------------------------------------------------------------------------
// Generic fp32 GEMM: C = [res +] act( A @ W + bias ), 64x64 tile
// ---------------------------------------------------------------------------
template<int ACT, int RES>
__global__ __launch_bounds__(256) void gemm64(
    const float* __restrict__ A, const float* __restrict__ W,
    const float* __restrict__ bias, const float* __restrict__ res,
    float* __restrict__ C, int M, int K, int Nn)
{
    __shared__ float As[64][17];
    __shared__ float Ws[16][64];
    const int tid = threadIdx.x;
    const int rb = blockIdx.x * 64, cb = blockIdx.y * 64;
    const int tx = tid & 15, ty = tid >> 4;

    float accv[4][4] = {};
    const int ar = tid >> 2;
    const int ak = (tid & 3) * 4;
    const int wk = tid >> 4;
    const int wc = (tid & 15) * 4;

    for (int k0 = 0; k0 < K; k0 += 16) {
        float4 av = make_float4(0.f,0.f,0.f,0.f);
        if (k0 + ak < K)
            av = *(const float4*)&A[(size_t)(rb+ar)*K + k0 + ak];
        float4 wv = make_float4(0.f,0.f,0.f,0.f);
        if (k0 + wk < K && cb + wc < Nn)
            wv = *(const float4*)&W[(size_t)(k0+wk)*Nn + cb + wc];
        __syncthreads();
        As[ar][ak+0]=av.x; As[ar][ak+1]=av.y; As[ar][ak+2]=av.z; As[ar][ak+3]=av.w;
        *(float4*)&Ws[wk][wc] = wv;
        __syncthreads();
        #pragma unroll
        for (int kk = 0; kk < 16; kk++) {
            float4 wrow = *(const float4*)&Ws[kk][tx*4];
            float wr[4] = {wrow.x, wrow.y, wrow.z, wrow.w};
            float aa[4] = {As[ty*4+0][kk], As[ty*4+1][kk],
                           As[ty*4+2][kk], As[ty*4+3][kk]};
            #pragma unroll
            for (int u = 0; u < 4; u++)
                #pragma unroll
                for (int v = 0; v < 4; v++)
                    accv[u][v] = fmaf(aa[u], wr[v], accv[u][v]);
        }
    }

    #pragma unroll
    for (int u = 0; u < 4; u++) {
        int r = rb + ty*4 + u;
        #pragma unroll
        for (int v = 0; v < 4; v++) {
            int c = cb + tx*4 + v;
            if (c < Nn) {
                float x = accv[u][v];
                if (bias) x += bias[c];
                if (ACT == 1) x = sspf(x);
                if (RES) x += res[(size_t)r*Nn + c];
                C[(size_t)r*Nn + c] = x;
            }
        }
    }
}

// ---------------------------------------------------------------------------
__global__ void pool_mean(const float* __restrict__ h, float* __restrict__ pooled) {
    int b = blockIdx.x;
    for (int f = threadIdx.x; f < HID; f += blockDim.x) {
        float s = 0.f;
        #pragma unroll
        for (int i = 0; i < NA; i++) s += h[(size_t)(b*NA+i)*HID + f];
        pooled[(size_t)b*HID + f] = s * (1.f/NA);
    }
}

// ---------------------------------------------------------------------------
extern "C" void kernel_launch(void* const* d_in, const int* in_sizes, int n_in,
                              void* d_out, int out_size, void* d_ws, size_t ws_size,
                              hipStream_t stream)
{
    const int*   z    = (const int*)  d_in[0];
    const float* pos  = (const float*)d_in[1];
    const float* emb  = (const float*)d_in[3];
    const float* mw1  = (const float*)d_in[4];
    const float* mb1  = (const float*)d_in[5];
    const float* mw2  = (const float*)d_in[6];
    const float* mb2  = (const float*)d_in[7];
    const float* l1w  = (const float*)d_in[8];
    const float* l2w  = (const float*)d_in[9];
    const float* l2b  = (const float*)d_in[10];
    const float* lw   = (const float*)d_in[11];
    const float* lb   = (const float*)d_in[12];
    const float* pw   = (const float*)d_in[13];
    const float* pb   = (const float*)d_in[14];

    char* p = (char*)d_ws;
    unsigned short* rbf_bf = (unsigned short*)p; p += (size_t)NEDGE*64*2;     // 8.39 MB
    float*          cwb    = (float*)p;          p += (size_t)NEDGE*4;        // 0.26 MB
    unsigned short* w1t    = (unsigned short*)p; p += (size_t)NL*608*64*2;    // 0.47 MB
    unsigned short* w2t    = (unsigned short*)p; p += (size_t)NL*640*608*2;   // 4.67 MB
    float* h      = (float*)p; p += (size_t)NTOT*HID*4;
    float* xj     = (float*)p; p += (size_t)NTOT*HID*4;
    float* mbuf   = (float*)p; p += (size_t)NTOT*HID*4;
    float* v1     = (float*)p; p += (size_t)NTOT*HID*4;
    float* pooled = (float*)p; p += (size_t)BB*HID*4;

    prep_edges<<<NEDGE/256, 256, 0, stream>>>(pos, rbf_bf, cwb);
    transpose_w1<<<NL*608, 64, 0, stream>>>(mw1, w1t);
    transpose_w2<<<NL*640, 256, 0, stream>>>(mw2, w2t);
    gather_h<<<NTOT, 256, 0, stream>>>(z, emb, h);

    dim3 gg(NTOT/64, (HID+63)/64);
    for (int l = 0; l < NL; l++) {
        const float* b1l  = mb1 + (size_t)l*HID;
        const float* b2l  = mb2 + (size_t)l*HID;
        const float* l1wl = l1w + (size_t)l*HID*HID;
        const float* l2wl = l2w + (size_t)l*HID*HID;
        const float* l2bl = l2b + (size_t)l*HID;
        const float* lwl  = lw  + (size_t)l*HID*HID;
        const float* lbl  = lb  + (size_t)l*HID;

        // xj = h @ lin1_w (no bias)
        gemm64<0,0><<<gg, 256, 0, stream>>>(h, l1wl, nullptr, nullptr, xj, NTOT, HID, HID);
        // fused filter-net + message -> mbuf
        edge_mfma<<<NTOT/2, 256, 0, stream>>>(rbf_bf, cwb, xj,
                                              w1t + (size_t)l*608*64, b1l,
                                              w2t + (size_t)l*640*608, b2l, mbuf);
        // v1 = ssp(mbuf @ lin2_w + lin2_b)
        gemm64<1,0><<<gg, 256, 0, stream>>>(mbuf, l2wl, l2bl, nullptr, v1, NTOT, HID, HID);
        // h = h + v1 @ lin_w + lin_b
        gemm64<0,1><<<gg, 256, 0, stream>>>(v1, lwl, lbl, h, h, NTOT, HID, HID);
    }

    pool_mean<<<BB, 256, 0, stream>>>(h, pooled);
    gemm64<0,0><<<dim3(1, (HID+63)/64), 256, 0, stream>>>(pooled, pw, pb, nullptr,
                                                          (float*)d_out, BB, HID, HID);
}

// Round 3
// 1706.149 us; speedup vs baseline: 4.6350x; 1.4922x over previous
//
#include <hip/hip_runtime.h>
#include <hip/hip_bf16.h>
#include <math.h>

#define BB 64
#define NA 32
#define NTOT 2048
#define HID 600
#define KP  640           // padded feature dim (weights, bf16 activations)
#define NG 50
#define NL 6
#define NEDGE 65536
#define TK 608            // K extent of t in edge kernel (38*16)

typedef __attribute__((ext_vector_type(8))) short short8;   // 8 bf16
typedef __attribute__((ext_vector_type(4))) float f32x4;

typedef __attribute__((address_space(1))) const void gvoid_t;
typedef __attribute__((address_space(3))) void lvoid_t;

__device__ __forceinline__ float sspf(float x) {
    return (x > 15.f) ? (x - 0.69314718056f)
                      : __logf(0.5f + 0.5f * __expf(x));
}
__device__ __forceinline__ unsigned short f2bf(float x) {
    union { float f; unsigned u; } v; v.f = x;
    unsigned r = v.u + 0x7FFF + ((v.u >> 16) & 1);   // RNE
    return (unsigned short)(r >> 16);
}

// ---------------------------------------------------------------------------
// Edge prep: rbf_bf[NEDGE][64] bf16 (k<50 valid, rest 0), cosw[NEDGE] fp32
// ---------------------------------------------------------------------------
__global__ void prep_edges(const float* __restrict__ pos,
                           unsigned short* __restrict__ rbf_bf,
                           float* __restrict__ cw) {
    int e = blockIdx.x * blockDim.x + threadIdx.x;
    if (e >= NEDGE) return;
    int b  = e >> 10;
    int ij = e & 1023;
    int i = ij >> 5, j = ij & 31;
    int ai = b*NA + i, aj = b*NA + j;
    float dx = pos[ai*3+0] - pos[aj*3+0];
    float dy = pos[ai*3+1] - pos[aj*3+1];
    float dz = pos[ai*3+2] - pos[aj*3+2];
    float sq = dx*dx + dy*dy + dz*dz;
    float d  = sqrtf(sq > 0.f ? sq : 1.f);
    float msk = ((sq <= 100.f) && (i != j)) ? 1.f : 0.f;
    cw[e] = 0.5f * (cosf(d * 0.31415926535f) + 1.f) * msk;
    const float step  = 10.f / 49.f;
    const float coeff = -0.5f / (step*step);
    #pragma unroll
    for (int g8 = 0; g8 < 8; g8++) {
        union { unsigned short us[8]; uint4 v; } u;
        #pragma unroll
        for (int q = 0; q < 8; q++) {
            int g = g8*8 + q;
            float t = d - step * (float)g;
            float val = (g < NG) ? __expf(coeff * t * t) : 0.f;
            u.us[q] = f2bf(val);
        }
        *(uint4*)(rbf_bf + (size_t)e*64 + g8*8) = u.v;
    }
}

// ---------------------------------------------------------------------------
// Tiled transpose: dst[l][f][k] = src[l][k][f], fp32[600][600] -> bf16[640][640]
// ---------------------------------------------------------------------------
__global__ void transpose_w(const float* __restrict__ src,
                            unsigned short* __restrict__ dst) {
    __shared__ float tile[64][65];
    int kb = blockIdx.x*64, fb = blockIdx.y*64, l = blockIdx.z;
    const float* s = src + (size_t)l*HID*HID;
    unsigned short* d = dst + (size_t)l*KP*KP;
    int tid = threadIdx.x;
    #pragma unroll 4
    for (int i = 0; i < 16; i++) {
        int idx = tid + 256*i;
        int r = idx >> 6, c = idx & 63;
        float v = 0.f;
        if (kb + r < HID && fb + c < HID) v = s[(size_t)(kb+r)*HID + fb + c];
        tile[r][c] = v;
    }
    __syncthreads();
    #pragma unroll 4
    for (int i = 0; i < 16; i++) {
        int idx = tid + 256*i;
        int fr = idx >> 6, kc = idx & 63;
        d[(size_t)(fb+fr)*KP + kb + kc] = f2bf(tile[kc][fr]);
    }
}

// ---------------------------------------------------------------------------
// w1t[l][640][64] bf16 : w1t[f][k] = w1[l][k][f]  (zero-padded)
// ---------------------------------------------------------------------------
__global__ void transpose_w1(const float* __restrict__ w1,
                             unsigned short* __restrict__ w1t) {
    int idx = blockIdx.x;
    int l = idx / KP, fr = idx - l*KP;
    int k = threadIdx.x;  // 64
    float v = (fr < HID && k < NG) ? w1[(size_t)l*NG*HID + (size_t)k*HID + fr] : 0.f;
    w1t[((size_t)l*KP + fr)*64 + k] = f2bf(v);
}

// ---------------------------------------------------------------------------
// h0 = emb[z] (fp32 + bf16-padded copy)
// ---------------------------------------------------------------------------
__global__ void gather_h(const int* __restrict__ z, const float* __restrict__ emb,
                         float* __restrict__ h, unsigned short* __restrict__ h_bf) {
    int n = blockIdx.x;
    int zi = z[n];
    for (int f = threadIdx.x; f < KP; f += blockDim.x) {
        float v = (f < HID) ? emb[(size_t)zi*HID + f] : 0.f;
        if (f < HID) h[(size_t)n*HID + f] = v;
        h_bf[(size_t)n*KP + f] = f2bf(v);
    }
}

// ---------------------------------------------------------------------------
// Fused edge filter + message, bf16 MFMA. One atom (32 edges) per block,
// 4 waves, VGPR<=128 -> 4 blocks/CU (16 waves/CU).
// Phase 1: t = ssp(rbf@w1+b1) -> LDS bf16 (XOR-swizzled, 39KB).
// Phase 2: W = t@w2t^T per wave over 10 f-tiles (s-blocking), epilogue
// (+b2)*cosw*xj reduce over all 32 j -> m_bf[i][f] directly.
// ---------------------------------------------------------------------------
__global__ __launch_bounds__(256, 4) void edge_mfma(
    const unsigned short* __restrict__ rbf_bf, const float* __restrict__ cw,
    const float* __restrict__ xj,
    const unsigned short* __restrict__ w1t, const float* __restrict__ b1,
    const unsigned short* __restrict__ w2t, const float* __restrict__ b2,
    unsigned short* __restrict__ m_bf)
{
    __shared__ __align__(16) char t_smem[32*1216];   // t[32][608] bf16 swizzled
    __shared__ float cw_s[NA];

    const int tid  = threadIdx.x;
    const int wave = tid >> 6, lane = tid & 63;
    const int cl = lane & 15, gr = lane >> 4;
    const int ai = blockIdx.x;           // atom 0..2047
    const int ebase = ai * NA;           // 32 edges of this atom
    const int jbase = ai & ~(NA-1);      // graph's first atom

    if (tid < NA) cw_s[tid] = cw[ebase + tid];

    // ---- phase 1: t = ssp(rbf @ w1 + b1) ----
    short8 a1[2][2];
    #pragma unroll
    for (int fr = 0; fr < 2; fr++)
        #pragma unroll
        for (int ks = 0; ks < 2; ks++)
            a1[fr][ks] = *(const short8*)(rbf_bf + (size_t)(ebase + fr*16 + cl)*64 + ks*32 + gr*8);

    for (int p = 0; p < 10; p++) {
        int ft = wave + 4*p;             // wave-uniform branch
        if (ft < 38) {
            f32x4 acc[2] = {};
            #pragma unroll
            for (int ks = 0; ks < 2; ks++) {
                short8 bfr = *(const short8*)(w1t + (size_t)(ft*16 + cl)*64 + ks*32 + gr*8);
                acc[0] = __builtin_amdgcn_mfma_f32_16x16x32_bf16(a1[0][ks], bfr, acc[0], 0, 0, 0);
                acc[1] = __builtin_amdgcn_mfma_f32_16x16x32_bf16(a1[1][ks], bfr, acc[1], 0, 0, 0);
            }
            int f = ft*16 + cl;
            float b1v = (f < HID) ? b1[f] : 0.f;     // f>=600: ssp(0)=0
            #pragma unroll
            for (int fr = 0; fr < 2; fr++)
                #pragma unroll
                for (int r = 0; r < 4; r++) {
                    int row = fr*16 + gr*4 + r;
                    float tv = sspf(acc[fr][r] + b1v);
                    int byt = row*1216 + f*2;
                    *(unsigned short*)(t_smem + (byt ^ ((row & 7) << 4))) = f2bf(tv);
                }
        }
    }
    __syncthreads();

    // ---- phase 2: W = t @ w2t^T, s=10 f-tiles per wave, fr=2 ----
    f32x4 acc[10][2] = {};
    const int ft0 = wave*10;
    for (int k0 = 0; k0 < TK; k0 += 32) {
        short8 a[2];
        #pragma unroll
        for (int fr = 0; fr < 2; fr++) {
            int row = fr*16 + cl;
            int byt = row*1216 + k0*2 + gr*16;
            a[fr] = *(const short8*)(t_smem + (byt ^ ((row & 7) << 4)));
        }
        #pragma unroll
        for (int s = 0; s < 10; s++) {
            short8 bfr = *(const short8*)(w2t + (size_t)((ft0 + s)*16 + cl)*KP + k0 + gr*8);
            acc[s][0] = __builtin_amdgcn_mfma_f32_16x16x32_bf16(a[0], bfr, acc[s][0], 0, 0, 0);
            acc[s][1] = __builtin_amdgcn_mfma_f32_16x16x32_bf16(a[1], bfr, acc[s][1], 0, 0, 0);
        }
    }

    // ---- epilogue: (+b2)*cosw*xj, reduce over 32 j, write m_bf ----
    #pragma unroll
    for (int s = 0; s < 10; s++) {
        int f = (ft0 + s)*16 + cl;
        if (f < HID) {                  // uniform across shfl partners (same cl)
            float b2v = b2[f];
            float s0 = 0.f;
            #pragma unroll
            for (int r = 0; r < 4; r++) {
                s0 += cw_s[gr*4 + r]      * (acc[s][0][r] + b2v) * xj[(size_t)(jbase + gr*4 + r)*HID + f];
                s0 += cw_s[16 + gr*4 + r] * (acc[s][1][r] + b2v) * xj[(size_t)(jbase + 16 + gr*4 + r)*HID + f];
            }
            s0 += __shfl_xor(s0, 16);
            s0 += __shfl_xor(s0, 32);
            if (gr == 0) m_bf[(size_t)ai*KP + f] = f2bf(s0);
        } else if (gr == 0 && f < KP) {
            m_bf[(size_t)ai*KP + f] = 0;  // keep pad cols zero
        }
    }
}

// ---------------------------------------------------------------------------
// bf16 MFMA GEMM: C = [res +] act( A @ Wt^T + bias )
// A[M][KP] bf16 (row-major), Wt[KP][KP] bf16 (f-major: Wt[f][k]).
// 64x64 C-tile, 4 waves (wave w -> cols w*16..w*16+15), BK=64 double-buffered
// via global_load_lds with pre-swizzled source (G21).
// ---------------------------------------------------------------------------
template<int ACT, int RES>
__global__ __launch_bounds__(256, 4) void gemm_bf(
    const unsigned short* __restrict__ A,
    const unsigned short* __restrict__ Wt,
    const float* __restrict__ bias,
    const float* __restrict__ res,
    float* __restrict__ Cf,
    unsigned short* __restrict__ Cb,
    int M)
{
    __shared__ __align__(16) unsigned short As[2][64*64];
    __shared__ __align__(16) unsigned short Bs[2][64*64];
    const int tid = threadIdx.x;
    const int wave = tid >> 6, lane = tid & 63;
    const int cl = lane & 15, gr = lane >> 4;
    const int row0 = blockIdx.x * 64, f0 = blockIdx.y * 64;

    // staging: chunk idx = i*256 + tid ; r = idx>>3, s = idx&7
    // global element offset pre-swizzled: 8*(s ^ (r&7)); (r+32)&7 == r&7
    const int r0 = tid >> 3, sc = tid & 7;
    const size_t swz = 8*(sc ^ (r0 & 7));
    const unsigned short* gA = A  + (size_t)(row0 + r0)*KP + swz;
    const unsigned short* gB = Wt + (size_t)(f0   + r0)*KP + swz;

    f32x4 acc[4] = {};

    // prologue stage k0=0 into buf 0
    {
        __builtin_amdgcn_global_load_lds((gvoid_t*)(gA),         (lvoid_t*)&As[0][wave*512],        16, 0, 0);
        __builtin_amdgcn_global_load_lds((gvoid_t*)(gA + 32*KP), (lvoid_t*)&As[0][2048 + wave*512], 16, 0, 0);
        __builtin_amdgcn_global_load_lds((gvoid_t*)(gB),         (lvoid_t*)&Bs[0][wave*512],        16, 0, 0);
        __builtin_amdgcn_global_load_lds((gvoid_t*)(gB + 32*KP), (lvoid_t*)&Bs[0][2048 + wave*512], 16, 0, 0);
    }

    int buf = 0;
    const int rb_ = wave*16 + cl;                 // B row (= output col idx in tile)
    const int bxor = (rb_ & 7) << 4;
    for (int t = 0; t < 10; t++) {
        __syncthreads();                          // drains vmcnt -> buf ready
        if (t < 9) {
            int k0 = (t+1)*64;
            __builtin_amdgcn_global_load_lds((gvoid_t*)(gA + k0),         (lvoid_t*)&As[buf^1][wave*512],        16, 0, 0);
            __builtin_amdgcn_global_load_lds((gvoid_t*)(gA + k0 + 32*KP), (lvoid_t*)&As[buf^1][2048 + wave*512], 16, 0, 0);
            __builtin_amdgcn_global_load_lds((gvoid_t*)(gB + k0),         (lvoid_t*)&Bs[buf^1][wave*512],        16, 0, 0);
            __builtin_amdgcn_global_load_lds((gvoid_t*)(gB + k0 + 32*KP), (lvoid_t*)&Bs[buf^1][2048 + wave*512], 16, 0, 0);
        }
        const char* pa = (const char*)As[buf];
        const char* pb = (const char*)Bs[buf];
        #pragma unroll
        for (int ks = 0; ks < 2; ks++) {
            short8 b = *(const short8*)(pb + (rb_*128 + ((ks*64 + gr*16) ^ bxor)));
            #pragma unroll
            for (int fr = 0; fr < 4; fr++) {
                int ra_ = fr*16 + cl;
                short8 a = *(const short8*)(pa + (ra_*128 + ((ks*64 + gr*16) ^ ((ra_ & 7) << 4))));
                acc[fr] = __builtin_amdgcn_mfma_f32_16x16x32_bf16(a, b, acc[fr], 0, 0, 0);
            }
        }
        buf ^= 1;
    }

    // epilogue
    const int fcol = f0 + wave*16 + cl;
    #pragma unroll
    for (int fr = 0; fr < 4; fr++) {
        #pragma unroll
        for (int r = 0; r < 4; r++) {
            int row = row0 + fr*16 + gr*4 + r;
            float x = acc[fr][r];
            if (fcol < HID) {
                if (bias) x += bias[fcol];
                if (ACT) x = sspf(x);
                if (RES) x += res[(size_t)row*HID + fcol];
                if (Cf) Cf[(size_t)row*HID + fcol] = x;
                if (Cb) Cb[(size_t)row*KP + fcol] = f2bf(x);
            } else if (Cb) {
                Cb[(size_t)row*KP + fcol] = 0;   // pad cols zero
            }
        }
    }
}

// ---------------------------------------------------------------------------
// fp32 GEMM (final 64x600 projection only)
// ---------------------------------------------------------------------------
template<int ACT, int RES>
__global__ __launch_bounds__(256) void gemm64(
    const float* __restrict__ A, const float* __restrict__ W,
    const float* __restrict__ bias, const float* __restrict__ res,
    float* __restrict__ C, int M, int K, int Nn)
{
    __shared__ float Asm[64][17];
    __shared__ float Wsm[16][64];
    const int tid = threadIdx.x;
    const int rb = blockIdx.x * 64, cb = blockIdx.y * 64;
    const int tx = tid & 15, ty = tid >> 4;

    float accv[4][4] = {};
    const int ar = tid >> 2;
    const int ak = (tid & 3) * 4;
    const int wk = tid >> 4;
    const int wc = (tid & 15) * 4;

    for (int k0 = 0; k0 < K; k0 += 16) {
        float4 av = make_float4(0.f,0.f,0.f,0.f);
        if (k0 + ak < K)
            av = *(const float4*)&A[(size_t)(rb+ar)*K + k0 + ak];
        float4 wv = make_float4(0.f,0.f,0.f,0.f);
        if (k0 + wk < K && cb + wc < Nn)
            wv = *(const float4*)&W[(size_t)(k0+wk)*Nn + cb + wc];
        __syncthreads();
        Asm[ar][ak+0]=av.x; Asm[ar][ak+1]=av.y; Asm[ar][ak+2]=av.z; Asm[ar][ak+3]=av.w;
        *(float4*)&Wsm[wk][wc] = wv;
        __syncthreads();
        #pragma unroll
        for (int kk = 0; kk < 16; kk++) {
            float4 wrow = *(const float4*)&Wsm[kk][tx*4];
            float wr[4] = {wrow.x, wrow.y, wrow.z, wrow.w};
            float aa[4] = {Asm[ty*4+0][kk], Asm[ty*4+1][kk],
                           Asm[ty*4+2][kk], Asm[ty*4+3][kk]};
            #pragma unroll
            for (int u = 0; u < 4; u++)
                #pragma unroll
                for (int v = 0; v < 4; v++)
                    accv[u][v] = fmaf(aa[u], wr[v], accv[u][v]);
        }
    }
    #pragma unroll
    for (int u = 0; u < 4; u++) {
        int r = rb + ty*4 + u;
        #pragma unroll
        for (int v = 0; v < 4; v++) {
            int c = cb + tx*4 + v;
            if (c < Nn) {
                float x = accv[u][v];
                if (bias) x += bias[c];
                if (ACT == 1) x = sspf(x);
                if (RES) x += res[(size_t)r*Nn + c];
                C[(size_t)r*Nn + c] = x;
            }
        }
    }
}

// ---------------------------------------------------------------------------
__global__ void pool_mean(const float* __restrict__ h, float* __restrict__ pooled) {
    int b = blockIdx.x;
    for (int f = threadIdx.x; f < HID; f += blockDim.x) {
        float s = 0.f;
        #pragma unroll
        for (int i = 0; i < NA; i++) s += h[(size_t)(b*NA+i)*HID + f];
        pooled[(size_t)b*HID + f] = s * (1.f/NA);
    }
}

// ---------------------------------------------------------------------------
extern "C" void kernel_launch(void* const* d_in, const int* in_sizes, int n_in,
                              void* d_out, int out_size, void* d_ws, size_t ws_size,
                              hipStream_t stream)
{
    const int*   z    = (const int*)  d_in[0];
    const float* pos  = (const float*)d_in[1];
    const float* emb  = (const float*)d_in[3];
    const float* mw1  = (const float*)d_in[4];
    const float* mb1  = (const float*)d_in[5];
    const float* mw2  = (const float*)d_in[6];
    const float* mb2  = (const float*)d_in[7];
    const float* l1w  = (const float*)d_in[8];
    const float* l2w  = (const float*)d_in[9];
    const float* l2b  = (const float*)d_in[10];
    const float* lw   = (const float*)d_in[11];
    const float* lb   = (const float*)d_in[12];
    const float* pw   = (const float*)d_in[13];
    const float* pb   = (const float*)d_in[14];

    char* p = (char*)d_ws;
    unsigned short* rbf_bf = (unsigned short*)p; p += (size_t)NEDGE*64*2;       // 8.4 MB
    float*          cwb    = (float*)p;          p += (size_t)NEDGE*4;          // 0.26 MB
    unsigned short* w1t    = (unsigned short*)p; p += (size_t)NL*KP*64*2;       // 0.49 MB
    unsigned short* wt2    = (unsigned short*)p; p += (size_t)NL*KP*KP*2;       // 4.92 MB
    unsigned short* wtl1   = (unsigned short*)p; p += (size_t)NL*KP*KP*2;
    unsigned short* wtl2   = (unsigned short*)p; p += (size_t)NL*KP*KP*2;
    unsigned short* wtl    = (unsigned short*)p; p += (size_t)NL*KP*KP*2;
    float*          h      = (float*)p;          p += (size_t)NTOT*HID*4;       // 4.9 MB
    unsigned short* h_bf   = (unsigned short*)p; p += (size_t)NTOT*KP*2;        // 2.6 MB
    float*          xj     = (float*)p;          p += (size_t)NTOT*HID*4;
    unsigned short* m_bf   = (unsigned short*)p; p += (size_t)NTOT*KP*2;
    unsigned short* v1_bf  = (unsigned short*)p; p += (size_t)NTOT*KP*2;
    float*          pooled = (float*)p;          p += (size_t)BB*HID*4;

    prep_edges<<<NEDGE/256, 256, 0, stream>>>(pos, rbf_bf, cwb);
    dim3 tg(10, 10, NL);
    transpose_w<<<tg, 256, 0, stream>>>(mw2, wt2);
    transpose_w<<<tg, 256, 0, stream>>>(l1w, wtl1);
    transpose_w<<<tg, 256, 0, stream>>>(l2w, wtl2);
    transpose_w<<<tg, 256, 0, stream>>>(lw,  wtl);
    transpose_w1<<<NL*KP, 64, 0, stream>>>(mw1, w1t);
    gather_h<<<NTOT, 256, 0, stream>>>(z, emb, h, h_bf);

    dim3 gg(NTOT/64, KP/64);
    for (int l = 0; l < NL; l++) {
        const float* b1l  = mb1 + (size_t)l*HID;
        const float* b2l  = mb2 + (size_t)l*HID;
        const float* l2bl = l2b + (size_t)l*HID;
        const float* lbl  = lb  + (size_t)l*HID;

        // xj = h @ lin1_w (fp32 out only)
        gemm_bf<0,0><<<gg, 256, 0, stream>>>(h_bf, wtl1 + (size_t)l*KP*KP,
                                             nullptr, nullptr, xj, nullptr, NTOT);
        // fused filter-net + message -> m_bf
        edge_mfma<<<NTOT, 256, 0, stream>>>(rbf_bf, cwb, xj,
                                            w1t + (size_t)l*KP*64, b1l,
                                            wt2 + (size_t)l*KP*KP, b2l, m_bf);
        // v1 = ssp(m @ lin2_w + lin2_b) (bf16 out only)
        gemm_bf<1,0><<<gg, 256, 0, stream>>>(m_bf, wtl2 + (size_t)l*KP*KP,
                                             l2bl, nullptr, nullptr, v1_bf, NTOT);
        // h = h + v1 @ lin_w + lin_b (fp32 + bf16 out)
        gemm_bf<0,1><<<gg, 256, 0, stream>>>(v1_bf, wtl + (size_t)l*KP*KP,
                                             lbl, h, h, h_bf, NTOT);
    }

    pool_mean<<<BB, 256, 0, stream>>>(h, pooled);
    gemm64<0,0><<<dim3(1, 10), 256, 0, stream>>>(pooled, pw, pb, nullptr,
                                                 (float*)d_out, BB, HID, HID);
}

// Round 5
// 1657.602 us; speedup vs baseline: 4.7708x; 1.0293x over previous
//
#include <hip/hip_runtime.h>
#include <hip/hip_bf16.h>
#include <math.h>

#define BB 64
#define NA 32
#define NTOT 2048
#define HID 600
#define KP  640           // padded feature dim (weights, bf16 activations)
#define NG 50
#define NL 6
#define NEDGE 65536
#define TK 608            // K extent of t in edge kernel (38*16)

typedef __attribute__((ext_vector_type(8))) short short8;   // 8 bf16
typedef __attribute__((ext_vector_type(4))) float f32x4;

typedef __attribute__((address_space(1))) const void gvoid_t;
typedef __attribute__((address_space(3))) void lvoid_t;

__device__ __forceinline__ float sspf(float x) {
    return (x > 15.f) ? (x - 0.69314718056f)
                      : __logf(0.5f + 0.5f * __expf(x));
}
__device__ __forceinline__ unsigned short f2bf(float x) {
    union { float f; unsigned u; } v; v.f = x;
    unsigned r = v.u + 0x7FFF + ((v.u >> 16) & 1);   // RNE
    return (unsigned short)(r >> 16);
}

// ---------------------------------------------------------------------------
// Edge prep: rbf_bf[NEDGE][64] bf16 (k<50 valid, rest 0), cosw[NEDGE] fp32
// ---------------------------------------------------------------------------
__global__ void prep_edges(const float* __restrict__ pos,
                           unsigned short* __restrict__ rbf_bf,
                           float* __restrict__ cw) {
    int e = blockIdx.x * blockDim.x + threadIdx.x;
    if (e >= NEDGE) return;
    int b  = e >> 10;
    int ij = e & 1023;
    int i = ij >> 5, j = ij & 31;
    int ai = b*NA + i, aj = b*NA + j;
    float dx = pos[ai*3+0] - pos[aj*3+0];
    float dy = pos[ai*3+1] - pos[aj*3+1];
    float dz = pos[ai*3+2] - pos[aj*3+2];
    float sq = dx*dx + dy*dy + dz*dz;
    float d  = sqrtf(sq > 0.f ? sq : 1.f);
    float msk = ((sq <= 100.f) && (i != j)) ? 1.f : 0.f;
    cw[e] = 0.5f * (cosf(d * 0.31415926535f) + 1.f) * msk;
    const float step  = 10.f / 49.f;
    const float coeff = -0.5f / (step*step);
    #pragma unroll
    for (int g8 = 0; g8 < 8; g8++) {
        union { unsigned short us[8]; uint4 v; } u;
        #pragma unroll
        for (int q = 0; q < 8; q++) {
            int g = g8*8 + q;
            float t = d - step * (float)g;
            float val = (g < NG) ? __expf(coeff * t * t) : 0.f;
            u.us[q] = f2bf(val);
        }
        *(uint4*)(rbf_bf + (size_t)e*64 + g8*8) = u.v;
    }
}

// ---------------------------------------------------------------------------
// Tiled transpose: dst[l][f][k] = src[l][k][f], fp32[600][600] -> bf16[640][640]
// ---------------------------------------------------------------------------
__global__ void transpose_w(const float* __restrict__ src,
                            unsigned short* __restrict__ dst) {
    __shared__ float tile[64][65];
    int kb = blockIdx.x*64, fb = blockIdx.y*64, l = blockIdx.z;
    const float* s = src + (size_t)l*HID*HID;
    unsigned short* d = dst + (size_t)l*KP*KP;
    int tid = threadIdx.x;
    #pragma unroll 4
    for (int i = 0; i < 16; i++) {
        int idx = tid + 256*i;
        int r = idx >> 6, c = idx & 63;
        float v = 0.f;
        if (kb + r < HID && fb + c < HID) v = s[(size_t)(kb+r)*HID + fb + c];
        tile[r][c] = v;
    }
    __syncthreads();
    #pragma unroll 4
    for (int i = 0; i < 16; i++) {
        int idx = tid + 256*i;
        int fr = idx >> 6, kc = idx & 63;
        d[(size_t)(fb+fr)*KP + kb + kc] = f2bf(tile[kc][fr]);
    }
}

// ---------------------------------------------------------------------------
// w1t[l][640][64] bf16 : w1t[f][k] = w1[l][k][f]  (zero-padded)
// ---------------------------------------------------------------------------
__global__ void transpose_w1(const float* __restrict__ w1,
                             unsigned short* __restrict__ w1t) {
    int idx = blockIdx.x;
    int l = idx / KP, fr = idx - l*KP;
    int k = threadIdx.x;  // 64
    float v = (fr < HID && k < NG) ? w1[(size_t)l*NG*HID + (size_t)k*HID + fr] : 0.f;
    w1t[((size_t)l*KP + fr)*64 + k] = f2bf(v);
}

// ---------------------------------------------------------------------------
// h0 = emb[z] (fp32 + bf16-padded copy)
// ---------------------------------------------------------------------------
__global__ void gather_h(const int* __restrict__ z, const float* __restrict__ emb,
                         float* __restrict__ h, unsigned short* __restrict__ h_bf) {
    int n = blockIdx.x;
    int zi = z[n];
    for (int f = threadIdx.x; f < KP; f += blockDim.x) {
        float v = (f < HID) ? emb[(size_t)zi*HID + f] : 0.f;
        if (f < HID) h[(size_t)n*HID + f] = v;
        h_bf[(size_t)n*KP + f] = f2bf(v);
    }
}

// ---------------------------------------------------------------------------
// Fused edge filter + message, bf16 MFMA. One atom (32 edges) per block,
// 4 waves. Phase 1: t = ssp(rbf@w1+b1) -> LDS bf16 (XOR-swizzled, 39KB).
// Phase 2: W = t@w2t^T, 2 groups x 5 f-tiles per wave, B double-buffer
// prefetched (hide L2 latency). Epilogue (+b2)*cosw*xj reduce over 32 j.
// NOTE (R4 bug): the XOR swizzle must be applied to the FULL byte offset
// including the k0 term — (base^m)+k != (base+k)^m when k overlaps mask bits.
// ---------------------------------------------------------------------------
__global__ __launch_bounds__(256, 3) void edge_mfma(
    const unsigned short* __restrict__ rbf_bf, const float* __restrict__ cw,
    const float* __restrict__ xj,
    const unsigned short* __restrict__ w1t, const float* __restrict__ b1,
    const unsigned short* __restrict__ w2t, const float* __restrict__ b2,
    unsigned short* __restrict__ m_bf)
{
    __shared__ __align__(16) char t_smem[32*1216];   // t[32][608] bf16 swizzled
    __shared__ float cw_s[NA];

    const int tid  = threadIdx.x;
    const int wave = tid >> 6, lane = tid & 63;
    const int cl = lane & 15, gr = lane >> 4;
    const int ai = blockIdx.x;           // atom 0..2047
    const int ebase = ai * NA;           // 32 edges of this atom
    const int jbase = ai & ~(NA-1);      // graph's first atom

    if (tid < NA) cw_s[tid] = cw[ebase + tid];

    // ---- phase 1: t = ssp(rbf @ w1 + b1) ----
    short8 a1[2][2];
    #pragma unroll
    for (int fr = 0; fr < 2; fr++)
        #pragma unroll
        for (int ks = 0; ks < 2; ks++)
            a1[fr][ks] = *(const short8*)(rbf_bf + (size_t)(ebase + fr*16 + cl)*64 + ks*32 + gr*8);

    for (int p = 0; p < 10; p++) {
        int ft = wave + 4*p;             // wave-uniform branch
        if (ft < 38) {
            f32x4 acc[2] = {};
            #pragma unroll
            for (int ks = 0; ks < 2; ks++) {
                short8 bfr = *(const short8*)(w1t + (size_t)(ft*16 + cl)*64 + ks*32 + gr*8);
                acc[0] = __builtin_amdgcn_mfma_f32_16x16x32_bf16(a1[0][ks], bfr, acc[0], 0, 0, 0);
                acc[1] = __builtin_amdgcn_mfma_f32_16x16x32_bf16(a1[1][ks], bfr, acc[1], 0, 0, 0);
            }
            int f = ft*16 + cl;
            float b1v = (f < HID) ? b1[f] : 0.f;     // f>=600: ssp(0)=0
            #pragma unroll
            for (int fr = 0; fr < 2; fr++)
                #pragma unroll
                for (int r = 0; r < 4; r++) {
                    int row = fr*16 + gr*4 + r;
                    float tv = sspf(acc[fr][r] + b1v);
                    int byt = row*1216 + f*2;
                    *(unsigned short*)(t_smem + (byt ^ ((row & 7) << 4))) = f2bf(tv);
                }
        }
    }
    __syncthreads();

    // ---- phase 2: W = t @ w2t^T, 2 grps x 5 f-tiles, B prefetch dbuf ----
    const int row0_ = cl, row1_ = 16 + cl;
    const int ab0 = row0_*1216 + gr*16;          // un-swizzled bases
    const int ab1 = row1_*1216 + gr*16;
    const int xr0 = (row0_ & 7) << 4;
    const int xr1 = (row1_ & 7) << 4;

    for (int grp = 0; grp < 2; grp++) {
        const int ft0 = wave*10 + grp*5;
        const unsigned short* pBg = w2t + (size_t)(ft0*16 + cl)*KP + gr*8;
        f32x4 acc[5][2] = {};
        short8 bA[5], bB[5];
        #pragma unroll
        for (int s = 0; s < 5; s++)
            bA[s] = *(const short8*)(pBg + (size_t)s*16*KP);

        int k0 = 0;
        #pragma unroll 1
        for (int it = 0; it < 9; it++) {
            // use bA @ k0, prefetch bB @ k0+32
            #pragma unroll
            for (int s = 0; s < 5; s++)
                bB[s] = *(const short8*)(pBg + (size_t)s*16*KP + k0 + 32);
            {
                short8 a0  = *(const short8*)(t_smem + ((ab0 + k0*2) ^ xr0));
                short8 a1_ = *(const short8*)(t_smem + ((ab1 + k0*2) ^ xr1));
                #pragma unroll
                for (int s = 0; s < 5; s++) {
                    acc[s][0] = __builtin_amdgcn_mfma_f32_16x16x32_bf16(a0,  bA[s], acc[s][0], 0, 0, 0);
                    acc[s][1] = __builtin_amdgcn_mfma_f32_16x16x32_bf16(a1_, bA[s], acc[s][1], 0, 0, 0);
                }
            }
            // use bB @ k0+32, prefetch bA @ k0+64 (tail k=608 hits zero-pad, unused)
            #pragma unroll
            for (int s = 0; s < 5; s++)
                bA[s] = *(const short8*)(pBg + (size_t)s*16*KP + k0 + 64);
            {
                short8 a0  = *(const short8*)(t_smem + ((ab0 + k0*2 + 64) ^ xr0));
                short8 a1_ = *(const short8*)(t_smem + ((ab1 + k0*2 + 64) ^ xr1));
                #pragma unroll
                for (int s = 0; s < 5; s++) {
                    acc[s][0] = __builtin_amdgcn_mfma_f32_16x16x32_bf16(a0,  bB[s], acc[s][0], 0, 0, 0);
                    acc[s][1] = __builtin_amdgcn_mfma_f32_16x16x32_bf16(a1_, bB[s], acc[s][1], 0, 0, 0);
                }
            }
            k0 += 64;
        }
        // final k-step k0 = 576 with bA
        {
            short8 a0  = *(const short8*)(t_smem + ((ab0 + 1152) ^ xr0));
            short8 a1_ = *(const short8*)(t_smem + ((ab1 + 1152) ^ xr1));
            #pragma unroll
            for (int s = 0; s < 5; s++) {
                acc[s][0] = __builtin_amdgcn_mfma_f32_16x16x32_bf16(a0,  bA[s], acc[s][0], 0, 0, 0);
                acc[s][1] = __builtin_amdgcn_mfma_f32_16x16x32_bf16(a1_, bA[s], acc[s][1], 0, 0, 0);
            }
        }

        // ---- epilogue: (+b2)*cosw*xj, reduce over 32 j, write m_bf ----
        #pragma unroll
        for (int s = 0; s < 5; s++) {
            int f = (ft0 + s)*16 + cl;
            if (f < HID) {              // uniform across shfl partners (same cl)
                float b2v = b2[f];
                float s0 = 0.f;
                #pragma unroll
                for (int r = 0; r < 4; r++) {
                    s0 += cw_s[gr*4 + r]      * (acc[s][0][r] + b2v) * xj[(size_t)(jbase + gr*4 + r)*HID + f];
                    s0 += cw_s[16 + gr*4 + r] * (acc[s][1][r] + b2v) * xj[(size_t)(jbase + 16 + gr*4 + r)*HID + f];
                }
                s0 += __shfl_xor(s0, 16);
                s0 += __shfl_xor(s0, 32);
                if (gr == 0) m_bf[(size_t)ai*KP + f] = f2bf(s0);
            } else if (gr == 0 && f < KP) {
                m_bf[(size_t)ai*KP + f] = 0;  // keep pad cols zero
            }
        }
    }
}

// ---------------------------------------------------------------------------
// bf16 MFMA GEMM: C = [res +] act( A @ Wt^T + bias )
// A[M][KP] bf16 (row-major), Wt[KP][KP] bf16 (f-major: Wt[f][k]).
// 64x64 C-tile, 4 waves, BK=64 double-buffered via global_load_lds with
// pre-swizzled source (G21).
// ---------------------------------------------------------------------------
template<int ACT, int RES>
__global__ __launch_bounds__(256, 4) void gemm_bf(
    const unsigned short* __restrict__ A,
    const unsigned short* __restrict__ Wt,
    const float* __restrict__ bias,
    const float* __restrict__ res,
    float* __restrict__ Cf,
    unsigned short* __restrict__ Cb,
    int M)
{
    __shared__ __align__(16) unsigned short As[2][64*64];
    __shared__ __align__(16) unsigned short Bs[2][64*64];
    const int tid = threadIdx.x;
    const int wave = tid >> 6, lane = tid & 63;
    const int cl = lane & 15, gr = lane >> 4;
    const int row0 = blockIdx.x * 64, f0 = blockIdx.y * 64;

    const int r0 = tid >> 3, sc = tid & 7;
    const size_t swz = 8*(sc ^ (r0 & 7));
    const unsigned short* gA = A  + (size_t)(row0 + r0)*KP + swz;
    const unsigned short* gB = Wt + (size_t)(f0   + r0)*KP + swz;

    f32x4 acc[4] = {};

    {
        __builtin_amdgcn_global_load_lds((gvoid_t*)(gA),         (lvoid_t*)&As[0][wave*512],        16, 0, 0);
        __builtin_amdgcn_global_load_lds((gvoid_t*)(gA + 32*KP), (lvoid_t*)&As[0][2048 + wave*512], 16, 0, 0);
        __builtin_amdgcn_global_load_lds((gvoid_t*)(gB),         (lvoid_t*)&Bs[0][wave*512],        16, 0, 0);
        __builtin_amdgcn_global_load_lds((gvoid_t*)(gB + 32*KP), (lvoid_t*)&Bs[0][2048 + wave*512], 16, 0, 0);
    }

    int buf = 0;
    const int rb_ = wave*16 + cl;
    const int bxor = (rb_ & 7) << 4;
    for (int t = 0; t < 10; t++) {
        __syncthreads();
        if (t < 9) {
            int k0 = (t+1)*64;
            __builtin_amdgcn_global_load_lds((gvoid_t*)(gA + k0),         (lvoid_t*)&As[buf^1][wave*512],        16, 0, 0);
            __builtin_amdgcn_global_load_lds((gvoid_t*)(gA + k0 + 32*KP), (lvoid_t*)&As[buf^1][2048 + wave*512], 16, 0, 0);
            __builtin_amdgcn_global_load_lds((gvoid_t*)(gB + k0),         (lvoid_t*)&Bs[buf^1][wave*512],        16, 0, 0);
            __builtin_amdgcn_global_load_lds((gvoid_t*)(gB + k0 + 32*KP), (lvoid_t*)&Bs[buf^1][2048 + wave*512], 16, 0, 0);
        }
        const char* pa = (const char*)As[buf];
        const char* pb = (const char*)Bs[buf];
        #pragma unroll
        for (int ks = 0; ks < 2; ks++) {
            short8 b = *(const short8*)(pb + (rb_*128 + ((ks*64 + gr*16) ^ bxor)));
            #pragma unroll
            for (int fr = 0; fr < 4; fr++) {
                int ra_ = fr*16 + cl;
                short8 a = *(const short8*)(pa + (ra_*128 + ((ks*64 + gr*16) ^ ((ra_ & 7) << 4))));
                acc[fr] = __builtin_amdgcn_mfma_f32_16x16x32_bf16(a, b, acc[fr], 0, 0, 0);
            }
        }
        buf ^= 1;
    }

    const int fcol = f0 + wave*16 + cl;
    #pragma unroll
    for (int fr = 0; fr < 4; fr++) {
        #pragma unroll
        for (int r = 0; r < 4; r++) {
            int row = row0 + fr*16 + gr*4 + r;
            float x = acc[fr][r];
            if (fcol < HID) {
                if (bias) x += bias[fcol];
                if (ACT) x = sspf(x);
                if (RES) x += res[(size_t)row*HID + fcol];
                if (Cf) Cf[(size_t)row*HID + fcol] = x;
                if (Cb) Cb[(size_t)row*KP + fcol] = f2bf(x);
            } else if (Cb) {
                Cb[(size_t)row*KP + fcol] = 0;
            }
        }
    }
}

// ---------------------------------------------------------------------------
// fp32 GEMM (final 64x600 projection only)
// ---------------------------------------------------------------------------
template<int ACT, int RES>
__global__ __launch_bounds__(256) void gemm64(
    const float* __restrict__ A, const float* __restrict__ W,
    const float* __restrict__ bias, const float* __restrict__ res,
    float* __restrict__ C, int M, int K, int Nn)
{
    __shared__ float Asm[64][17];
    __shared__ float Wsm[16][64];
    const int tid = threadIdx.x;
    const int rb = blockIdx.x * 64, cb = blockIdx.y * 64;
    const int tx = tid & 15, ty = tid >> 4;

    float accv[4][4] = {};
    const int ar = tid >> 2;
    const int ak = (tid & 3) * 4;
    const int wk = tid >> 4;
    const int wc = (tid & 15) * 4;

    for (int k0 = 0; k0 < K; k0 += 16) {
        float4 av = make_float4(0.f,0.f,0.f,0.f);
        if (k0 + ak < K)
            av = *(const float4*)&A[(size_t)(rb+ar)*K + k0 + ak];
        float4 wv = make_float4(0.f,0.f,0.f,0.f);
        if (k0 + wk < K && cb + wc < Nn)
            wv = *(const float4*)&W[(size_t)(k0+wk)*Nn + cb + wc];
        __syncthreads();
        Asm[ar][ak+0]=av.x; Asm[ar][ak+1]=av.y; Asm[ar][ak+2]=av.z; Asm[ar][ak+3]=av.w;
        *(float4*)&Wsm[wk][wc] = wv;
        __syncthreads();
        #pragma unroll
        for (int kk = 0; kk < 16; kk++) {
            float4 wrow = *(const float4*)&Wsm[kk][tx*4];
            float wr[4] = {wrow.x, wrow.y, wrow.z, wrow.w};
            float aa[4] = {Asm[ty*4+0][kk], Asm[ty*4+1][kk],
                           Asm[ty*4+2][kk], Asm[ty*4+3][kk]};
            #pragma unroll
            for (int u = 0; u < 4; u++)
                #pragma unroll
                for (int v = 0; v < 4; v++)
                    accv[u][v] = fmaf(aa[u], wr[v], accv[u][v]);
        }
    }
    #pragma unroll
    for (int u = 0; u < 4; u++) {
        int r = rb + ty*4 + u;
        #pragma unroll
        for (int v = 0; v < 4; v++) {
            int c = cb + tx*4 + v;
            if (c < Nn) {
                float x = accv[u][v];
                if (bias) x += bias[c];
                if (ACT == 1) x = sspf(x);
                if (RES) x += res[(size_t)r*Nn + c];
                C[(size_t)r*Nn + c] = x;
            }
        }
    }
}

// ---------------------------------------------------------------------------
__global__ void pool_mean(const float* __restrict__ h, float* __restrict__ pooled) {
    int b = blockIdx.x;
    for (int f = threadIdx.x; f < HID; f += blockDim.x) {
        float s = 0.f;
        #pragma unroll
        for (int i = 0; i < NA; i++) s += h[(size_t)(b*NA+i)*HID + f];
        pooled[(size_t)b*HID + f] = s * (1.f/NA);
    }
}

// ---------------------------------------------------------------------------
extern "C" void kernel_launch(void* const* d_in, const int* in_sizes, int n_in,
                              void* d_out, int out_size, void* d_ws, size_t ws_size,
                              hipStream_t stream)
{
    const int*   z    = (const int*)  d_in[0];
    const float* pos  = (const float*)d_in[1];
    const float* emb  = (const float*)d_in[3];
    const float* mw1  = (const float*)d_in[4];
    const float* mb1  = (const float*)d_in[5];
    const float* mw2  = (const float*)d_in[6];
    const float* mb2  = (const float*)d_in[7];
    const float* l1w  = (const float*)d_in[8];
    const float* l2w  = (const float*)d_in[9];
    const float* l2b  = (const float*)d_in[10];
    const float* lw   = (const float*)d_in[11];
    const float* lb   = (const float*)d_in[12];
    const float* pw   = (const float*)d_in[13];
    const float* pb   = (const float*)d_in[14];

    char* p = (char*)d_ws;
    unsigned short* rbf_bf = (unsigned short*)p; p += (size_t)NEDGE*64*2;       // 8.4 MB
    float*          cwb    = (float*)p;          p += (size_t)NEDGE*4;          // 0.26 MB
    unsigned short* w1t    = (unsigned short*)p; p += (size_t)NL*KP*64*2;       // 0.49 MB
    unsigned short* wt2    = (unsigned short*)p; p += (size_t)NL*KP*KP*2;       // 4.92 MB
    unsigned short* wtl1   = (unsigned short*)p; p += (size_t)NL*KP*KP*2;
    unsigned short* wtl2   = (unsigned short*)p; p += (size_t)NL*KP*KP*2;
    unsigned short* wtl    = (unsigned short*)p; p += (size_t)NL*KP*KP*2;
    float*          h      = (float*)p;          p += (size_t)NTOT*HID*4;       // 4.9 MB
    unsigned short* h_bf   = (unsigned short*)p; p += (size_t)NTOT*KP*2;        // 2.6 MB
    float*          xj     = (float*)p;          p += (size_t)NTOT*HID*4;
    unsigned short* m_bf   = (unsigned short*)p; p += (size_t)NTOT*KP*2;
    unsigned short* v1_bf  = (unsigned short*)p; p += (size_t)NTOT*KP*2;
    float*          pooled = (float*)p;          p += (size_t)BB*HID*4;

    prep_edges<<<NEDGE/256, 256, 0, stream>>>(pos, rbf_bf, cwb);
    dim3 tg(10, 10, NL);
    transpose_w<<<tg, 256, 0, stream>>>(mw2, wt2);
    transpose_w<<<tg, 256, 0, stream>>>(l1w, wtl1);
    transpose_w<<<tg, 256, 0, stream>>>(l2w, wtl2);
    transpose_w<<<tg, 256, 0, stream>>>(lw,  wtl);
    transpose_w1<<<NL*KP, 64, 0, stream>>>(mw1, w1t);
    gather_h<<<NTOT, 256, 0, stream>>>(z, emb, h, h_bf);

    dim3 gg(NTOT/64, KP/64);
    for (int l = 0; l < NL; l++) {
        const float* b1l  = mb1 + (size_t)l*HID;
        const float* b2l  = mb2 + (size_t)l*HID;
        const float* l2bl = l2b + (size_t)l*HID;
        const float* lbl  = lb  + (size_t)l*HID;

        // xj = h @ lin1_w (fp32 out only)
        gemm_bf<0,0><<<gg, 256, 0, stream>>>(h_bf, wtl1 + (size_t)l*KP*KP,
                                             nullptr, nullptr, xj, nullptr, NTOT);
        // fused filter-net + message -> m_bf
        edge_mfma<<<NTOT, 256, 0, stream>>>(rbf_bf, cwb, xj,
                                            w1t + (size_t)l*KP*64, b1l,
                                            wt2 + (size_t)l*KP*KP, b2l, m_bf);
        // v1 = ssp(m @ lin2_w + lin2_b) (bf16 out only)
        gemm_bf<1,0><<<gg, 256, 0, stream>>>(m_bf, wtl2 + (size_t)l*KP*KP,
                                             l2bl, nullptr, nullptr, v1_bf, NTOT);
        // h = h + v1 @ lin_w + lin_b (fp32 + bf16 out)
        gemm_bf<0,1><<<gg, 256, 0, stream>>>(v1_bf, wtl + (size_t)l*KP*KP,
                                             lbl, h, h, h_bf, NTOT);
    }

    pool_mean<<<BB, 256, 0, stream>>>(h, pooled);
    gemm64<0,0><<<dim3(1, 10), 256, 0, stream>>>(pooled, pw, pb, nullptr,
                                                 (float*)d_out, BB, HID, HID);
}

// Round 6
// 1278.947 us; speedup vs baseline: 6.1833x; 1.2961x over previous
//
#include <hip/hip_runtime.h>
#include <hip/hip_bf16.h>
#include <math.h>

#define BB 64
#define NA 32
#define NTOT 2048
#define HID 600
#define KP  640           // padded feature dim (weights, bf16 activations)
#define NG 50
#define NL 6
#define NEDGE 65536
#define TK 608            // K extent of t in edge kernel (38*16)

typedef __attribute__((ext_vector_type(8))) short short8;   // 8 bf16
typedef __attribute__((ext_vector_type(4))) float f32x4;

typedef __attribute__((address_space(1))) const void gvoid_t;
typedef __attribute__((address_space(3))) void lvoid_t;

__device__ __forceinline__ float sspf(float x) {
    return (x > 15.f) ? (x - 0.69314718056f)
                      : __logf(0.5f + 0.5f * __expf(x));
}
__device__ __forceinline__ unsigned short f2bf(float x) {
    union { float f; unsigned u; } v; v.f = x;
    unsigned r = v.u + 0x7FFF + ((v.u >> 16) & 1);   // RNE
    return (unsigned short)(r >> 16);
}

// ---------------------------------------------------------------------------
// Edge prep: rbf_bf[NEDGE][64] bf16 (k<50 valid, rest 0), cosw[NEDGE] fp32
// ---------------------------------------------------------------------------
__global__ void prep_edges(const float* __restrict__ pos,
                           unsigned short* __restrict__ rbf_bf,
                           float* __restrict__ cw) {
    int e = blockIdx.x * blockDim.x + threadIdx.x;
    if (e >= NEDGE) return;
    int b  = e >> 10;
    int ij = e & 1023;
    int i = ij >> 5, j = ij & 31;
    int ai = b*NA + i, aj = b*NA + j;
    float dx = pos[ai*3+0] - pos[aj*3+0];
    float dy = pos[ai*3+1] - pos[aj*3+1];
    float dz = pos[ai*3+2] - pos[aj*3+2];
    float sq = dx*dx + dy*dy + dz*dz;
    float d  = sqrtf(sq > 0.f ? sq : 1.f);
    float msk = ((sq <= 100.f) && (i != j)) ? 1.f : 0.f;
    cw[e] = 0.5f * (cosf(d * 0.31415926535f) + 1.f) * msk;
    const float step  = 10.f / 49.f;
    const float coeff = -0.5f / (step*step);
    #pragma unroll
    for (int g8 = 0; g8 < 8; g8++) {
        union { unsigned short us[8]; uint4 v; } u;
        #pragma unroll
        for (int q = 0; q < 8; q++) {
            int g = g8*8 + q;
            float t = d - step * (float)g;
            float val = (g < NG) ? __expf(coeff * t * t) : 0.f;
            u.us[q] = f2bf(val);
        }
        *(uint4*)(rbf_bf + (size_t)e*64 + g8*8) = u.v;
    }
}

// ---------------------------------------------------------------------------
// Tiled transpose: dst[l][f][k] = src[l][k][f], fp32[600][600] -> bf16[640][640]
// ---------------------------------------------------------------------------
__global__ void transpose_w(const float* __restrict__ src,
                            unsigned short* __restrict__ dst) {
    __shared__ float tile[64][65];
    int kb = blockIdx.x*64, fb = blockIdx.y*64, l = blockIdx.z;
    const float* s = src + (size_t)l*HID*HID;
    unsigned short* d = dst + (size_t)l*KP*KP;
    int tid = threadIdx.x;
    #pragma unroll 4
    for (int i = 0; i < 16; i++) {
        int idx = tid + 256*i;
        int r = idx >> 6, c = idx & 63;
        float v = 0.f;
        if (kb + r < HID && fb + c < HID) v = s[(size_t)(kb+r)*HID + fb + c];
        tile[r][c] = v;
    }
    __syncthreads();
    #pragma unroll 4
    for (int i = 0; i < 16; i++) {
        int idx = tid + 256*i;
        int fr = idx >> 6, kc = idx & 63;
        d[(size_t)(fb+fr)*KP + kb + kc] = f2bf(tile[kc][fr]);
    }
}

// ---------------------------------------------------------------------------
// w1t[l][640][64] bf16 : w1t[f][k] = w1[l][k][f]  (zero-padded)
// ---------------------------------------------------------------------------
__global__ void transpose_w1(const float* __restrict__ w1,
                             unsigned short* __restrict__ w1t) {
    int idx = blockIdx.x;
    int l = idx / KP, fr = idx - l*KP;
    int k = threadIdx.x;  // 64
    float v = (fr < HID && k < NG) ? w1[(size_t)l*NG*HID + (size_t)k*HID + fr] : 0.f;
    w1t[((size_t)l*KP + fr)*64 + k] = f2bf(v);
}

// ---------------------------------------------------------------------------
// h0 = emb[z] (fp32 + bf16-padded copy)
// ---------------------------------------------------------------------------
__global__ void gather_h(const int* __restrict__ z, const float* __restrict__ emb,
                         float* __restrict__ h, unsigned short* __restrict__ h_bf) {
    int n = blockIdx.x;
    int zi = z[n];
    for (int f = threadIdx.x; f < KP; f += blockDim.x) {
        float v = (f < HID) ? emb[(size_t)zi*HID + f] : 0.f;
        if (f < HID) h[(size_t)n*HID + f] = v;
        h_bf[(size_t)n*KP + f] = f2bf(v);
    }
}

// ---------------------------------------------------------------------------
// Fused edge filter + message, bf16 MFMA. TWO atoms (64 edges) per block,
// 4 waves. Phase 1: t = ssp(rbf@w1+b1) -> LDS bf16 [64][608] (XOR-swizzled,
// 78 KB -> 2 blocks/CU). Phase 2: W = t@w2t^T, 2 groups x 5 f-tiles per wave,
// fr=4 (both atoms), TRIPLE-buffered B prefetch at distance 2 k-steps
// (~200 cyc own-wave cover). Epilogue (+b2)*cosw*xj reduce over 32 j per atom.
// XOR swizzle always applied to the FULL byte offset (R4 lesson).
// ---------------------------------------------------------------------------
__global__ __launch_bounds__(256, 2) void edge_mfma(
    const unsigned short* __restrict__ rbf_bf, const float* __restrict__ cw,
    const float* __restrict__ xj,
    const unsigned short* __restrict__ w1t, const float* __restrict__ b1,
    const unsigned short* __restrict__ w2t, const float* __restrict__ b2,
    unsigned short* __restrict__ m_bf)
{
    __shared__ __align__(16) char t_smem[64*1216];   // t[64][608] bf16 swizzled
    __shared__ float cw_s[64];

    const int tid  = threadIdx.x;
    const int wave = tid >> 6, lane = tid & 63;
    const int cl = lane & 15, gr = lane >> 4;
    const int i0 = blockIdx.x * 2;       // first atom
    const int ebase = i0 * NA;           // 64 consecutive edges
    const int jbase = i0 & ~(NA-1);      // graph's first atom

    if (tid < 64) cw_s[tid] = cw[ebase + tid];

    // ---- phase 1: t = ssp(rbf @ w1 + b1), M=64 ----
    {
        short8 a1[4][2];
        #pragma unroll
        for (int fr = 0; fr < 4; fr++)
            #pragma unroll
            for (int ks = 0; ks < 2; ks++)
                a1[fr][ks] = *(const short8*)(rbf_bf + (size_t)(ebase + fr*16 + cl)*64 + ks*32 + gr*8);

        for (int p = 0; p < 10; p++) {
            int ft = wave + 4*p;             // wave-uniform branch
            if (ft < 38) {
                f32x4 acc[4] = {};
                #pragma unroll
                for (int ks = 0; ks < 2; ks++) {
                    short8 bfr = *(const short8*)(w1t + (size_t)(ft*16 + cl)*64 + ks*32 + gr*8);
                    #pragma unroll
                    for (int fr = 0; fr < 4; fr++)
                        acc[fr] = __builtin_amdgcn_mfma_f32_16x16x32_bf16(a1[fr][ks], bfr, acc[fr], 0, 0, 0);
                }
                int f = ft*16 + cl;
                float b1v = (f < HID) ? b1[f] : 0.f;     // f>=600: ssp(0)=0
                #pragma unroll
                for (int fr = 0; fr < 4; fr++)
                    #pragma unroll
                    for (int r = 0; r < 4; r++) {
                        int row = fr*16 + gr*4 + r;
                        float tv = sspf(acc[fr][r] + b1v);
                        int byt = row*1216 + f*2;
                        *(unsigned short*)(t_smem + (byt ^ ((row & 7) << 4))) = f2bf(tv);
                    }
            }
        }
    }
    __syncthreads();

    // ---- phase 2: W = t @ w2t^T, 2 grps x 5 f-tiles, fr=4, 3-buf prefetch ----
    #define LOAD_S(Sb, kk)                                                        \
        _Pragma("unroll")                                                         \
        for (int s = 0; s < 5; s++)                                               \
            Sb[s] = *(const short8*)(pBg + (size_t)s*16*KP + (kk));

    #define MFMA_STEP(Sb, kk)                                                     \
        {                                                                         \
            short8 a_[4];                                                         \
            _Pragma("unroll")                                                     \
            for (int fr = 0; fr < 4; fr++) {                                      \
                int row = fr*16 + cl;                                             \
                a_[fr] = *(const short8*)(t_smem +                                \
                          ((row*1216 + (kk)*2 + gr*16) ^ ((row & 7) << 4)));      \
            }                                                                     \
            _Pragma("unroll")                                                     \
            for (int s = 0; s < 5; s++)                                           \
                _Pragma("unroll")                                                 \
                for (int fr = 0; fr < 4; fr++)                                    \
                    acc[s][fr] = __builtin_amdgcn_mfma_f32_16x16x32_bf16(         \
                        a_[fr], Sb[s], acc[s][fr], 0, 0, 0);                      \
        }

    for (int grp = 0; grp < 2; grp++) {
        const int ft0 = wave*10 + grp*5;
        const unsigned short* pBg = w2t + (size_t)(ft0*16 + cl)*KP + gr*8;
        f32x4 acc[5][4] = {};
        short8 S0[5], S1[5], S2[5];

        LOAD_S(S0, 0)
        LOAD_S(S1, 32)

        #pragma unroll 1
        for (int it = 0; it < 6; it++) {
            const int k0 = it*96;
            LOAD_S(S2, k0+64)
            MFMA_STEP(S0, k0)
            LOAD_S(S0, k0+96)
            MFMA_STEP(S1, k0+32)
            LOAD_S(S1, k0+128)
            MFMA_STEP(S2, k0+64)
        }
        MFMA_STEP(S0, 576)     // tail (S1@608 prefetched into zero-pad, unused)

        // ---- epilogue: (+b2)*cosw*xj, reduce over 32 j per atom ----
        #pragma unroll
        for (int s = 0; s < 5; s++) {
            int f = (ft0 + s)*16 + cl;
            if (f < HID) {              // uniform across shfl partners (same cl)
                float b2v = b2[f];
                float s0 = 0.f, s1 = 0.f;
                #pragma unroll
                for (int r = 0; r < 4; r++) {
                    float xa = xj[(size_t)(jbase + gr*4 + r)*HID + f];
                    float xb = xj[(size_t)(jbase + 16 + gr*4 + r)*HID + f];
                    s0 += cw_s[gr*4 + r]      * (acc[s][0][r] + b2v) * xa;
                    s0 += cw_s[16 + gr*4 + r] * (acc[s][1][r] + b2v) * xb;
                    s1 += cw_s[32 + gr*4 + r] * (acc[s][2][r] + b2v) * xa;
                    s1 += cw_s[48 + gr*4 + r] * (acc[s][3][r] + b2v) * xb;
                }
                s0 += __shfl_xor(s0, 16); s0 += __shfl_xor(s0, 32);
                s1 += __shfl_xor(s1, 16); s1 += __shfl_xor(s1, 32);
                if (gr == 0) {
                    m_bf[(size_t)i0*KP + f]     = f2bf(s0);
                    m_bf[(size_t)(i0+1)*KP + f] = f2bf(s1);
                }
            } else if (gr == 0 && f < KP) {
                m_bf[(size_t)i0*KP + f]     = 0;   // keep pad cols zero
                m_bf[(size_t)(i0+1)*KP + f] = 0;
            }
        }
    }
    #undef LOAD_S
    #undef MFMA_STEP
}

// ---------------------------------------------------------------------------
// bf16 MFMA GEMM: C = [res +] act( A @ Wt^T + bias )
// A[M][KP] bf16 (row-major), Wt[KP][KP] bf16 (f-major: Wt[f][k]).
// 64x64 C-tile, 4 waves, BK=64 double-buffered via global_load_lds with
// pre-swizzled source (G21).
// ---------------------------------------------------------------------------
template<int ACT, int RES>
__global__ __launch_bounds__(256, 4) void gemm_bf(
    const unsigned short* __restrict__ A,
    const unsigned short* __restrict__ Wt,
    const float* __restrict__ bias,
    const float* __restrict__ res,
    float* __restrict__ Cf,
    unsigned short* __restrict__ Cb,
    int M)
{
    __shared__ __align__(16) unsigned short As[2][64*64];
    __shared__ __align__(16) unsigned short Bs[2][64*64];
    const int tid = threadIdx.x;
    const int wave = tid >> 6, lane = tid & 63;
    const int cl = lane & 15, gr = lane >> 4;
    const int row0 = blockIdx.x * 64, f0 = blockIdx.y * 64;

    const int r0 = tid >> 3, sc = tid & 7;
    const size_t swz = 8*(sc ^ (r0 & 7));
    const unsigned short* gA = A  + (size_t)(row0 + r0)*KP + swz;
    const unsigned short* gB = Wt + (size_t)(f0   + r0)*KP + swz;

    f32x4 acc[4] = {};

    {
        __builtin_amdgcn_global_load_lds((gvoid_t*)(gA),         (lvoid_t*)&As[0][wave*512],        16, 0, 0);
        __builtin_amdgcn_global_load_lds((gvoid_t*)(gA + 32*KP), (lvoid_t*)&As[0][2048 + wave*512], 16, 0, 0);
        __builtin_amdgcn_global_load_lds((gvoid_t*)(gB),         (lvoid_t*)&Bs[0][wave*512],        16, 0, 0);
        __builtin_amdgcn_global_load_lds((gvoid_t*)(gB + 32*KP), (lvoid_t*)&Bs[0][2048 + wave*512], 16, 0, 0);
    }

    int buf = 0;
    const int rb_ = wave*16 + cl;
    const int bxor = (rb_ & 7) << 4;
    for (int t = 0; t < 10; t++) {
        __syncthreads();
        if (t < 9) {
            int k0 = (t+1)*64;
            __builtin_amdgcn_global_load_lds((gvoid_t*)(gA + k0),         (lvoid_t*)&As[buf^1][wave*512],        16, 0, 0);
            __builtin_amdgcn_global_load_lds((gvoid_t*)(gA + k0 + 32*KP), (lvoid_t*)&As[buf^1][2048 + wave*512], 16, 0, 0);
            __builtin_amdgcn_global_load_lds((gvoid_t*)(gB + k0),         (lvoid_t*)&Bs[buf^1][wave*512],        16, 0, 0);
            __builtin_amdgcn_global_load_lds((gvoid_t*)(gB + k0 + 32*KP), (lvoid_t*)&Bs[buf^1][2048 + wave*512], 16, 0, 0);
        }
        const char* pa = (const char*)As[buf];
        const char* pb = (const char*)Bs[buf];
        #pragma unroll
        for (int ks = 0; ks < 2; ks++) {
            short8 b = *(const short8*)(pb + (rb_*128 + ((ks*64 + gr*16) ^ bxor)));
            #pragma unroll
            for (int fr = 0; fr < 4; fr++) {
                int ra_ = fr*16 + cl;
                short8 a = *(const short8*)(pa + (ra_*128 + ((ks*64 + gr*16) ^ ((ra_ & 7) << 4))));
                acc[fr] = __builtin_amdgcn_mfma_f32_16x16x32_bf16(a, b, acc[fr], 0, 0, 0);
            }
        }
        buf ^= 1;
    }

    const int fcol = f0 + wave*16 + cl;
    #pragma unroll
    for (int fr = 0; fr < 4; fr++) {
        #pragma unroll
        for (int r = 0; r < 4; r++) {
            int row = row0 + fr*16 + gr*4 + r;
            float x = acc[fr][r];
            if (fcol < HID) {
                if (bias) x += bias[fcol];
                if (ACT) x = sspf(x);
                if (RES) x += res[(size_t)row*HID + fcol];
                if (Cf) Cf[(size_t)row*HID + fcol] = x;
                if (Cb) Cb[(size_t)row*KP + fcol] = f2bf(x);
            } else if (Cb) {
                Cb[(size_t)row*KP + fcol] = 0;
            }
        }
    }
}

// ---------------------------------------------------------------------------
// fp32 GEMM (final 64x600 projection only)
// ---------------------------------------------------------------------------
template<int ACT, int RES>
__global__ __launch_bounds__(256) void gemm64(
    const float* __restrict__ A, const float* __restrict__ W,
    const float* __restrict__ bias, const float* __restrict__ res,
    float* __restrict__ C, int M, int K, int Nn)
{
    __shared__ float Asm[64][17];
    __shared__ float Wsm[16][64];
    const int tid = threadIdx.x;
    const int rb = blockIdx.x * 64, cb = blockIdx.y * 64;
    const int tx = tid & 15, ty = tid >> 4;

    float accv[4][4] = {};
    const int ar = tid >> 2;
    const int ak = (tid & 3) * 4;
    const int wk = tid >> 4;
    const int wc = (tid & 15) * 4;

    for (int k0 = 0; k0 < K; k0 += 16) {
        float4 av = make_float4(0.f,0.f,0.f,0.f);
        if (k0 + ak < K)
            av = *(const float4*)&A[(size_t)(rb+ar)*K + k0 + ak];
        float4 wv = make_float4(0.f,0.f,0.f,0.f);
        if (k0 + wk < K && cb + wc < Nn)
            wv = *(const float4*)&W[(size_t)(k0+wk)*Nn + cb + wc];
        __syncthreads();
        Asm[ar][ak+0]=av.x; Asm[ar][ak+1]=av.y; Asm[ar][ak+2]=av.z; Asm[ar][ak+3]=av.w;
        *(float4*)&Wsm[wk][wc] = wv;
        __syncthreads();
        #pragma unroll
        for (int kk = 0; kk < 16; kk++) {
            float4 wrow = *(const float4*)&Wsm[kk][tx*4];
            float wr[4] = {wrow.x, wrow.y, wrow.z, wrow.w};
            float aa[4] = {Asm[ty*4+0][kk], Asm[ty*4+1][kk],
                           Asm[ty*4+2][kk], Asm[ty*4+3][kk]};
            #pragma unroll
            for (int u = 0; u < 4; u++)
                #pragma unroll
                for (int v = 0; v < 4; v++)
                    accv[u][v] = fmaf(aa[u], wr[v], accv[u][v]);
        }
    }
    #pragma unroll
    for (int u = 0; u < 4; u++) {
        int r = rb + ty*4 + u;
        #pragma unroll
        for (int v = 0; v < 4; v++) {
            int c = cb + tx*4 + v;
            if (c < Nn) {
                float x = accv[u][v];
                if (bias) x += bias[c];
                if (ACT == 1) x = sspf(x);
                if (RES) x += res[(size_t)r*Nn + c];
                C[(size_t)r*Nn + c] = x;
            }
        }
    }
}

// ---------------------------------------------------------------------------
__global__ void pool_mean(const float* __restrict__ h, float* __restrict__ pooled) {
    int b = blockIdx.x;
    for (int f = threadIdx.x; f < HID; f += blockDim.x) {
        float s = 0.f;
        #pragma unroll
        for (int i = 0; i < NA; i++) s += h[(size_t)(b*NA+i)*HID + f];
        pooled[(size_t)b*HID + f] = s * (1.f/NA);
    }
}

// ---------------------------------------------------------------------------
extern "C" void kernel_launch(void* const* d_in, const int* in_sizes, int n_in,
                              void* d_out, int out_size, void* d_ws, size_t ws_size,
                              hipStream_t stream)
{
    const int*   z    = (const int*)  d_in[0];
    const float* pos  = (const float*)d_in[1];
    const float* emb  = (const float*)d_in[3];
    const float* mw1  = (const float*)d_in[4];
    const float* mb1  = (const float*)d_in[5];
    const float* mw2  = (const float*)d_in[6];
    const float* mb2  = (const float*)d_in[7];
    const float* l1w  = (const float*)d_in[8];
    const float* l2w  = (const float*)d_in[9];
    const float* l2b  = (const float*)d_in[10];
    const float* lw   = (const float*)d_in[11];
    const float* lb   = (const float*)d_in[12];
    const float* pw   = (const float*)d_in[13];
    const float* pb   = (const float*)d_in[14];

    char* p = (char*)d_ws;
    unsigned short* rbf_bf = (unsigned short*)p; p += (size_t)NEDGE*64*2;       // 8.4 MB
    float*          cwb    = (float*)p;          p += (size_t)NEDGE*4;          // 0.26 MB
    unsigned short* w1t    = (unsigned short*)p; p += (size_t)NL*KP*64*2;       // 0.49 MB
    unsigned short* wt2    = (unsigned short*)p; p += (size_t)NL*KP*KP*2;       // 4.92 MB
    unsigned short* wtl1   = (unsigned short*)p; p += (size_t)NL*KP*KP*2;
    unsigned short* wtl2   = (unsigned short*)p; p += (size_t)NL*KP*KP*2;
    unsigned short* wtl    = (unsigned short*)p; p += (size_t)NL*KP*KP*2;
    float*          h      = (float*)p;          p += (size_t)NTOT*HID*4;       // 4.9 MB
    unsigned short* h_bf   = (unsigned short*)p; p += (size_t)NTOT*KP*2;        // 2.6 MB
    float*          xj     = (float*)p;          p += (size_t)NTOT*HID*4;
    unsigned short* m_bf   = (unsigned short*)p; p += (size_t)NTOT*KP*2;
    unsigned short* v1_bf  = (unsigned short*)p; p += (size_t)NTOT*KP*2;
    float*          pooled = (float*)p;          p += (size_t)BB*HID*4;

    prep_edges<<<NEDGE/256, 256, 0, stream>>>(pos, rbf_bf, cwb);
    dim3 tg(10, 10, NL);
    transpose_w<<<tg, 256, 0, stream>>>(mw2, wt2);
    transpose_w<<<tg, 256, 0, stream>>>(l1w, wtl1);
    transpose_w<<<tg, 256, 0, stream>>>(l2w, wtl2);
    transpose_w<<<tg, 256, 0, stream>>>(lw,  wtl);
    transpose_w1<<<NL*KP, 64, 0, stream>>>(mw1, w1t);
    gather_h<<<NTOT, 256, 0, stream>>>(z, emb, h, h_bf);

    dim3 gg(NTOT/64, KP/64);
    for (int l = 0; l < NL; l++) {
        const float* b1l  = mb1 + (size_t)l*HID;
        const float* b2l  = mb2 + (size_t)l*HID;
        const float* l2bl = l2b + (size_t)l*HID;
        const float* lbl  = lb  + (size_t)l*HID;

        // xj = h @ lin1_w (fp32 out only)
        gemm_bf<0,0><<<gg, 256, 0, stream>>>(h_bf, wtl1 + (size_t)l*KP*KP,
                                             nullptr, nullptr, xj, nullptr, NTOT);
        // fused filter-net + message -> m_bf
        edge_mfma<<<NTOT/2, 256, 0, stream>>>(rbf_bf, cwb, xj,
                                              w1t + (size_t)l*KP*64, b1l,
                                              wt2 + (size_t)l*KP*KP, b2l, m_bf);
        // v1 = ssp(m @ lin2_w + lin2_b) (bf16 out only)
        gemm_bf<1,0><<<gg, 256, 0, stream>>>(m_bf, wtl2 + (size_t)l*KP*KP,
                                             l2bl, nullptr, nullptr, v1_bf, NTOT);
        // h = h + v1 @ lin_w + lin_b (fp32 + bf16 out)
        gemm_bf<0,1><<<gg, 256, 0, stream>>>(v1_bf, wtl + (size_t)l*KP*KP,
                                             lbl, h, h, h_bf, NTOT);
    }

    pool_mean<<<BB, 256, 0, stream>>>(h, pooled);
    gemm64<0,0><<<dim3(1, 10), 256, 0, stream>>>(pooled, pw, pb, nullptr,
                                                 (float*)d_out, BB, HID, HID);
}

// Round 7
// 1074.363 us; speedup vs baseline: 7.3607x; 1.1904x over previous
//
#include <hip/hip_runtime.h>
#include <hip/hip_bf16.h>
#include <math.h>

#define BB 64
#define NA 32
#define NTOT 2048
#define HID 600
#define KP  640           // padded feature dim (weights, bf16 activations)
#define NG 50
#define NL 6
#define NEDGE 65536
#define TK 608            // K extent of t in edge kernel (38*16)
#define W2G_L (8*19*5*512)   // elems per layer of packed w2 = 389120

typedef __attribute__((ext_vector_type(8))) short short8;   // 8 bf16
typedef __attribute__((ext_vector_type(4))) float f32x4;

typedef __attribute__((address_space(1))) const void gvoid_t;
typedef __attribute__((address_space(3))) void lvoid_t;

__device__ __forceinline__ float sspf(float x) {
    return (x > 15.f) ? (x - 0.69314718056f)
                      : __logf(0.5f + 0.5f * __expf(x));
}
__device__ __forceinline__ unsigned short f2bf(float x) {
    union { float f; unsigned u; } v; v.f = x;
    unsigned r = v.u + 0x7FFF + ((v.u >> 16) & 1);   // RNE
    return (unsigned short)(r >> 16);
}

// ---------------------------------------------------------------------------
// Edge prep: rbf_bf[NEDGE][64] bf16 (k<50 valid, rest 0), cosw[NEDGE] fp32
// ---------------------------------------------------------------------------
__global__ void prep_edges(const float* __restrict__ pos,
                           unsigned short* __restrict__ rbf_bf,
                           float* __restrict__ cw) {
    int e = blockIdx.x * blockDim.x + threadIdx.x;
    if (e >= NEDGE) return;
    int b  = e >> 10;
    int ij = e & 1023;
    int i = ij >> 5, j = ij & 31;
    int ai = b*NA + i, aj = b*NA + j;
    float dx = pos[ai*3+0] - pos[aj*3+0];
    float dy = pos[ai*3+1] - pos[aj*3+1];
    float dz = pos[ai*3+2] - pos[aj*3+2];
    float sq = dx*dx + dy*dy + dz*dz;
    float d  = sqrtf(sq > 0.f ? sq : 1.f);
    float msk = ((sq <= 100.f) && (i != j)) ? 1.f : 0.f;
    cw[e] = 0.5f * (cosf(d * 0.31415926535f) + 1.f) * msk;
    const float step  = 10.f / 49.f;
    const float coeff = -0.5f / (step*step);
    #pragma unroll
    for (int g8 = 0; g8 < 8; g8++) {
        union { unsigned short us[8]; uint4 v; } u;
        #pragma unroll
        for (int q = 0; q < 8; q++) {
            int g = g8*8 + q;
            float t = d - step * (float)g;
            float val = (g < NG) ? __expf(coeff * t * t) : 0.f;
            u.us[q] = f2bf(val);
        }
        *(uint4*)(rbf_bf + (size_t)e*64 + g8*8) = u.v;
    }
}

// ---------------------------------------------------------------------------
// Tiled transpose: dst[l][f][k] = src[l][k][f], fp32[600][600] -> bf16[640][640]
// (used for lin1/lin2/lin weights)
// ---------------------------------------------------------------------------
__global__ void transpose_w(const float* __restrict__ src,
                            unsigned short* __restrict__ dst) {
    __shared__ float tile[64][65];
    int kb = blockIdx.x*64, fb = blockIdx.y*64, l = blockIdx.z;
    const float* s = src + (size_t)l*HID*HID;
    unsigned short* d = dst + (size_t)l*KP*KP;
    int tid = threadIdx.x;
    #pragma unroll 4
    for (int i = 0; i < 16; i++) {
        int idx = tid + 256*i;
        int r = idx >> 6, c = idx & 63;
        float v = 0.f;
        if (kb + r < HID && fb + c < HID) v = s[(size_t)(kb+r)*HID + fb + c];
        tile[r][c] = v;
    }
    __syncthreads();
    #pragma unroll 4
    for (int i = 0; i < 16; i++) {
        int idx = tid + 256*i;
        int fr = idx >> 6, kc = idx & 63;
        d[(size_t)(fb+fr)*KP + kb + kc] = f2bf(tile[kc][fr]);
    }
}

// ---------------------------------------------------------------------------
// Pack w2 into per-wave-group tiled layout:
// w2g[l][g 8][t 19][s 5][cl 16][gr 4][e 8] = w2[l][k][f],
//   f = g*80 + s*16 + cl,  k = t*32 + gr*8 + e   (zero-padded outside 600)
// So per (wave-group, k-step) the 5 B-fragments are contiguous 5 KB.
// ---------------------------------------------------------------------------
__global__ void pack_w2(const float* __restrict__ src,
                        unsigned short* __restrict__ dst) {
    int t = blockIdx.x, g = blockIdx.y, l = blockIdx.z;
    #pragma unroll
    for (int i = 0; i < 10; i++) {
        int flat = i*256 + threadIdx.x;          // 0..2559
        int cl = flat & 15;
        int e  = (flat >> 4) & 7;
        int gr = (flat >> 7) & 3;
        int s  = flat >> 9;
        int f = g*80 + s*16 + cl;
        int k = t*32 + gr*8 + e;
        float v = (f < HID && k < HID) ? src[(size_t)l*HID*HID + (size_t)k*HID + f] : 0.f;
        size_t di = (size_t)l*W2G_L + (((size_t)(g*19 + t)*5 + s)*512) + cl*32 + gr*8 + e;
        dst[di] = f2bf(v);
    }
}

// ---------------------------------------------------------------------------
// w1t[l][640][64] bf16 : w1t[f][k] = w1[l][k][f]  (zero-padded)
// ---------------------------------------------------------------------------
__global__ void transpose_w1(const float* __restrict__ w1,
                             unsigned short* __restrict__ w1t) {
    int idx = blockIdx.x;
    int l = idx / KP, fr = idx - l*KP;
    int k = threadIdx.x;  // 64
    float v = (fr < HID && k < NG) ? w1[(size_t)l*NG*HID + (size_t)k*HID + fr] : 0.f;
    w1t[((size_t)l*KP + fr)*64 + k] = f2bf(v);
}

// ---------------------------------------------------------------------------
// h0 = emb[z] (fp32 + bf16-padded copy)
// ---------------------------------------------------------------------------
__global__ void gather_h(const int* __restrict__ z, const float* __restrict__ emb,
                         float* __restrict__ h, unsigned short* __restrict__ h_bf) {
    int n = blockIdx.x;
    int zi = z[n];
    for (int f = threadIdx.x; f < KP; f += blockDim.x) {
        float v = (f < HID) ? emb[(size_t)zi*HID + f] : 0.f;
        if (f < HID) h[(size_t)n*HID + f] = v;
        h_bf[(size_t)n*KP + f] = f2bf(v);
    }
}

// ---------------------------------------------------------------------------
// Fused edge filter + message, bf16 MFMA. TWO atoms (64 edges) per block,
// 4 waves. Phase 1: t = ssp(rbf@w1+b1) -> LDS bf16 [64][608], swizzle mask
// ((row>>2)&3)<<4 (bits 4-5 only -> k-steps are pure imm offsets on the read).
// Phase 2: 2 grps x 5 f-tiles per wave, fr=4, triple-buffered B prefetch from
// the packed w2g stream (1 pointer bump + imm offsets). Epilogue reads xjT
// (transposed) with float4s, (+b2)*cosw*xj reduce over 32 j per atom.
// ---------------------------------------------------------------------------
__global__ __launch_bounds__(256, 2) void edge_mfma(
    const unsigned short* __restrict__ rbf_bf, const float* __restrict__ cw,
    const float* __restrict__ xjT,
    const unsigned short* __restrict__ w1t, const float* __restrict__ b1,
    const unsigned short* __restrict__ w2g, const float* __restrict__ b2,
    unsigned short* __restrict__ m_bf)
{
    __shared__ __align__(16) char t_smem[64*1216];   // t[64][608] bf16 swizzled
    __shared__ float cw_s[64];

    const int tid  = threadIdx.x;
    const int wave = tid >> 6, lane = tid & 63;
    const int cl = lane & 15, gr = lane >> 4;
    const int i0 = blockIdx.x * 2;       // first atom
    const int ebase = i0 * NA;           // 64 consecutive edges
    const int jbase = i0 & ~(NA-1);      // graph's first atom

    if (tid < 64) cw_s[tid] = cw[ebase + tid];

    // ---- phase 1: t = ssp(rbf @ w1 + b1), M=64 ----
    {
        short8 a1[4][2];
        #pragma unroll
        for (int fr = 0; fr < 4; fr++)
            #pragma unroll
            for (int ks = 0; ks < 2; ks++)
                a1[fr][ks] = *(const short8*)(rbf_bf + (size_t)(ebase + fr*16 + cl)*64 + ks*32 + gr*8);

        for (int p = 0; p < 10; p++) {
            int ft = wave + 4*p;             // wave-uniform branch
            if (ft < 38) {
                f32x4 acc[4] = {};
                #pragma unroll
                for (int ks = 0; ks < 2; ks++) {
                    short8 bfr = *(const short8*)(w1t + (size_t)(ft*16 + cl)*64 + ks*32 + gr*8);
                    #pragma unroll
                    for (int fr = 0; fr < 4; fr++)
                        acc[fr] = __builtin_amdgcn_mfma_f32_16x16x32_bf16(a1[fr][ks], bfr, acc[fr], 0, 0, 0);
                }
                int f = ft*16 + cl;
                float b1v = (f < HID) ? b1[f] : 0.f;     // f>=600: ssp(0)=0
                #pragma unroll
                for (int fr = 0; fr < 4; fr++)
                    #pragma unroll
                    for (int r = 0; r < 4; r++) {
                        int row = fr*16 + gr*4 + r;
                        float tv = sspf(acc[fr][r] + b1v);
                        int byt = row*1216 + f*2;
                        *(unsigned short*)(t_smem + (byt ^ (((row >> 2) & 3) << 4))) = f2bf(tv);
                    }
            }
        }
    }
    __syncthreads();

    // ---- phase 2 ----
    int abase[4];
    #pragma unroll
    for (int fr = 0; fr < 4; fr++) {
        int row = fr*16 + cl;
        abase[fr] = (row*1216 + gr*16) ^ (((row >> 2) & 3) << 4);
    }

    #define LOADB(Sb, OFF)                                                       \
        _Pragma("unroll")                                                        \
        for (int s = 0; s < 5; s++)                                              \
            Sb[s] = *(const short8*)(pB + (OFF) + s*1024 - 2048);

    #define ASTEP(Sb, KO)                                                        \
        {                                                                        \
            short8 a_[4];                                                        \
            _Pragma("unroll")                                                    \
            for (int fr = 0; fr < 4; fr++)                                       \
                a_[fr] = *(const short8*)(pa + abase[fr] + (KO));                 \
            _Pragma("unroll")                                                    \
            for (int s = 0; s < 5; s++)                                          \
                _Pragma("unroll")                                                \
                for (int fr = 0; fr < 4; fr++)                                   \
                    acc[s][fr] = __builtin_amdgcn_mfma_f32_16x16x32_bf16(        \
                        a_[fr], Sb[s], acc[s][fr], 0, 0, 0);                     \
        }

    for (int grp = 0; grp < 2; grp++) {
        const int g = wave*2 + grp;          // wave-group 0..7, f range g*80..
        const char* pB = (const char*)(w2g + (size_t)g*19*5*512) + cl*64 + gr*16 + 2048;
        const char* pa = t_smem;
        f32x4 acc[5][4] = {};
        short8 S0[5], S1[5], S2[5];

        LOADB(S0, 0)          // k-step 0
        LOADB(S1, 5120)       // k-step 1

        #pragma unroll 1
        for (int it = 0; it < 6; it++) {
            LOADB(S2, 10240)  // step n+2
            ASTEP(S0, 0)
            LOADB(S0, 15360)  // step n+3
            ASTEP(S1, 64)
            LOADB(S1, 20480)  // step n+4
            ASTEP(S2, 128)
            pB += 15360;
            pa += 192;
        }
        ASTEP(S0, 0)          // k-step 18 (pa = t_smem + 1152)

        // ---- epilogue: (+b2)*cosw*xjT, reduce over 32 j per atom ----
        #pragma unroll
        for (int s = 0; s < 5; s++) {
            int f = (g*5 + s)*16 + cl;
            if (f < HID) {              // uniform across shfl partners (same cl)
                float b2v = b2[f];
                const float* xcol = xjT + (size_t)f*NTOT + jbase;
                float4 xa = *(const float4*)(xcol + gr*4);
                float4 xb = *(const float4*)(xcol + 16 + gr*4);
                const float* xaf = (const float*)&xa;
                const float* xbf = (const float*)&xb;
                float s0 = 0.f, s1 = 0.f;
                #pragma unroll
                for (int r = 0; r < 4; r++) {
                    s0 += cw_s[gr*4 + r]      * (acc[s][0][r] + b2v) * xaf[r];
                    s0 += cw_s[16 + gr*4 + r] * (acc[s][1][r] + b2v) * xbf[r];
                    s1 += cw_s[32 + gr*4 + r] * (acc[s][2][r] + b2v) * xaf[r];
                    s1 += cw_s[48 + gr*4 + r] * (acc[s][3][r] + b2v) * xbf[r];
                }
                s0 += __shfl_xor(s0, 16); s0 += __shfl_xor(s0, 32);
                s1 += __shfl_xor(s1, 16); s1 += __shfl_xor(s1, 32);
                if (gr == 0) {
                    m_bf[(size_t)i0*KP + f]     = f2bf(s0);
                    m_bf[(size_t)(i0+1)*KP + f] = f2bf(s1);
                }
            } else if (gr == 0 && f < KP) {
                m_bf[(size_t)i0*KP + f]     = 0;   // keep pad cols zero
                m_bf[(size_t)(i0+1)*KP + f] = 0;
            }
        }
    }
    #undef LOADB
    #undef ASTEP
}

// ---------------------------------------------------------------------------
// bf16 MFMA GEMM: C = [res +] act( A @ Wt^T + bias )
// A[M][KP] bf16 (row-major), Wt[KP][KP] bf16 (f-major: Wt[f][k]).
// 64x64 C-tile, 4 waves, BK=64 double-buffered via global_load_lds with
// pre-swizzled source (G21). Optional transposed fp32 output CfT[f][row].
// ---------------------------------------------------------------------------
template<int ACT, int RES>
__global__ __launch_bounds__(256, 4) void gemm_bf(
    const unsigned short* __restrict__ A,
    const unsigned short* __restrict__ Wt,
    const float* __restrict__ bias,
    const float* __restrict__ res,
    float* __restrict__ Cf,
    float* __restrict__ CfT,
    unsigned short* __restrict__ Cb,
    int M)
{
    __shared__ __align__(16) unsigned short As[2][64*64];
    __shared__ __align__(16) unsigned short Bs[2][64*64];
    const int tid = threadIdx.x;
    const int wave = tid >> 6, lane = tid & 63;
    const int cl = lane & 15, gr = lane >> 4;
    const int row0 = blockIdx.x * 64, f0 = blockIdx.y * 64;

    const int r0 = tid >> 3, sc = tid & 7;
    const size_t swz = 8*(sc ^ (r0 & 7));
    const unsigned short* gA = A  + (size_t)(row0 + r0)*KP + swz;
    const unsigned short* gB = Wt + (size_t)(f0   + r0)*KP + swz;

    f32x4 acc[4] = {};

    {
        __builtin_amdgcn_global_load_lds((gvoid_t*)(gA),         (lvoid_t*)&As[0][wave*512],        16, 0, 0);
        __builtin_amdgcn_global_load_lds((gvoid_t*)(gA + 32*KP), (lvoid_t*)&As[0][2048 + wave*512], 16, 0, 0);
        __builtin_amdgcn_global_load_lds((gvoid_t*)(gB),         (lvoid_t*)&Bs[0][wave*512],        16, 0, 0);
        __builtin_amdgcn_global_load_lds((gvoid_t*)(gB + 32*KP), (lvoid_t*)&Bs[0][2048 + wave*512], 16, 0, 0);
    }

    int buf = 0;
    const int rb_ = wave*16 + cl;
    const int bxor = (rb_ & 7) << 4;
    for (int t = 0; t < 10; t++) {
        __syncthreads();
        if (t < 9) {
            int k0 = (t+1)*64;
            __builtin_amdgcn_global_load_lds((gvoid_t*)(gA + k0),         (lvoid_t*)&As[buf^1][wave*512],        16, 0, 0);
            __builtin_amdgcn_global_load_lds((gvoid_t*)(gA + k0 + 32*KP), (lvoid_t*)&As[buf^1][2048 + wave*512], 16, 0, 0);
            __builtin_amdgcn_global_load_lds((gvoid_t*)(gB + k0),         (lvoid_t*)&Bs[buf^1][wave*512],        16, 0, 0);
            __builtin_amdgcn_global_load_lds((gvoid_t*)(gB + k0 + 32*KP), (lvoid_t*)&Bs[buf^1][2048 + wave*512], 16, 0, 0);
        }
        const char* pa = (const char*)As[buf];
        const char* pb = (const char*)Bs[buf];
        #pragma unroll
        for (int ks = 0; ks < 2; ks++) {
            short8 b = *(const short8*)(pb + (rb_*128 + ((ks*64 + gr*16) ^ bxor)));
            #pragma unroll
            for (int fr = 0; fr < 4; fr++) {
                int ra_ = fr*16 + cl;
                short8 a = *(const short8*)(pa + (ra_*128 + ((ks*64 + gr*16) ^ ((ra_ & 7) << 4))));
                acc[fr] = __builtin_amdgcn_mfma_f32_16x16x32_bf16(a, b, acc[fr], 0, 0, 0);
            }
        }
        buf ^= 1;
    }

    const int fcol = f0 + wave*16 + cl;
    #pragma unroll
    for (int fr = 0; fr < 4; fr++) {
        #pragma unroll
        for (int r = 0; r < 4; r++) {
            int row = row0 + fr*16 + gr*4 + r;
            float x = acc[fr][r];
            if (fcol < HID) {
                if (bias) x += bias[fcol];
                if (ACT) x = sspf(x);
                if (RES) x += res[(size_t)row*HID + fcol];
                if (Cf)  Cf[(size_t)row*HID + fcol] = x;
                if (CfT) CfT[(size_t)fcol*NTOT + row] = x;
                if (Cb)  Cb[(size_t)row*KP + fcol] = f2bf(x);
            } else if (Cb) {
                Cb[(size_t)row*KP + fcol] = 0;
            }
        }
    }
}

// ---------------------------------------------------------------------------
// fp32 GEMM (final 64x600 projection only)
// ---------------------------------------------------------------------------
template<int ACT, int RES>
__global__ __launch_bounds__(256) void gemm64(
    const float* __restrict__ A, const float* __restrict__ W,
    const float* __restrict__ bias, const float* __restrict__ res,
    float* __restrict__ C, int M, int K, int Nn)
{
    __shared__ float Asm[64][17];
    __shared__ float Wsm[16][64];
    const int tid = threadIdx.x;
    const int rb = blockIdx.x * 64, cb = blockIdx.y * 64;
    const int tx = tid & 15, ty = tid >> 4;

    float accv[4][4] = {};
    const int ar = tid >> 2;
    const int ak = (tid & 3) * 4;
    const int wk = tid >> 4;
    const int wc = (tid & 15) * 4;

    for (int k0 = 0; k0 < K; k0 += 16) {
        float4 av = make_float4(0.f,0.f,0.f,0.f);
        if (k0 + ak < K)
            av = *(const float4*)&A[(size_t)(rb+ar)*K + k0 + ak];
        float4 wv = make_float4(0.f,0.f,0.f,0.f);
        if (k0 + wk < K && cb + wc < Nn)
            wv = *(const float4*)&W[(size_t)(k0+wk)*Nn + cb + wc];
        __syncthreads();
        Asm[ar][ak+0]=av.x; Asm[ar][ak+1]=av.y; Asm[ar][ak+2]=av.z; Asm[ar][ak+3]=av.w;
        *(float4*)&Wsm[wk][wc] = wv;
        __syncthreads();
        #pragma unroll
        for (int kk = 0; kk < 16; kk++) {
            float4 wrow = *(const float4*)&Wsm[kk][tx*4];
            float wr[4] = {wrow.x, wrow.y, wrow.z, wrow.w};
            float aa[4] = {Asm[ty*4+0][kk], Asm[ty*4+1][kk],
                           Asm[ty*4+2][kk], Asm[ty*4+3][kk]};
            #pragma unroll
            for (int u = 0; u < 4; u++)
                #pragma unroll
                for (int v = 0; v < 4; v++)
                    accv[u][v] = fmaf(aa[u], wr[v], accv[u][v]);
        }
    }
    #pragma unroll
    for (int u = 0; u < 4; u++) {
        int r = rb + ty*4 + u;
        #pragma unroll
        for (int v = 0; v < 4; v++) {
            int c = cb + tx*4 + v;
            if (c < Nn) {
                float x = accv[u][v];
                if (bias) x += bias[c];
                if (ACT == 1) x = sspf(x);
                if (RES) x += res[(size_t)r*Nn + c];
                C[(size_t)r*Nn + c] = x;
            }
        }
    }
}

// ---------------------------------------------------------------------------
__global__ void pool_mean(const float* __restrict__ h, float* __restrict__ pooled) {
    int b = blockIdx.x;
    for (int f = threadIdx.x; f < HID; f += blockDim.x) {
        float s = 0.f;
        #pragma unroll
        for (int i = 0; i < NA; i++) s += h[(size_t)(b*NA+i)*HID + f];
        pooled[(size_t)b*HID + f] = s * (1.f/NA);
    }
}

// ---------------------------------------------------------------------------
extern "C" void kernel_launch(void* const* d_in, const int* in_sizes, int n_in,
                              void* d_out, int out_size, void* d_ws, size_t ws_size,
                              hipStream_t stream)
{
    const int*   z    = (const int*)  d_in[0];
    const float* pos  = (const float*)d_in[1];
    const float* emb  = (const float*)d_in[3];
    const float* mw1  = (const float*)d_in[4];
    const float* mb1  = (const float*)d_in[5];
    const float* mw2  = (const float*)d_in[6];
    const float* mb2  = (const float*)d_in[7];
    const float* l1w  = (const float*)d_in[8];
    const float* l2w  = (const float*)d_in[9];
    const float* l2b  = (const float*)d_in[10];
    const float* lw   = (const float*)d_in[11];
    const float* lb   = (const float*)d_in[12];
    const float* pw   = (const float*)d_in[13];
    const float* pb   = (const float*)d_in[14];

    char* p = (char*)d_ws;
    unsigned short* rbf_bf = (unsigned short*)p; p += (size_t)NEDGE*64*2;       // 8.4 MB
    float*          cwb    = (float*)p;          p += (size_t)NEDGE*4;          // 0.26 MB
    unsigned short* w1t    = (unsigned short*)p; p += (size_t)NL*KP*64*2;       // 0.49 MB
    unsigned short* w2g    = (unsigned short*)p; p += (size_t)NL*W2G_L*2;       // 4.67 MB
    unsigned short* wtl1   = (unsigned short*)p; p += (size_t)NL*KP*KP*2;       // 4.92 MB
    unsigned short* wtl2   = (unsigned short*)p; p += (size_t)NL*KP*KP*2;
    unsigned short* wtl    = (unsigned short*)p; p += (size_t)NL*KP*KP*2;
    float*          h      = (float*)p;          p += (size_t)NTOT*HID*4;       // 4.9 MB
    unsigned short* h_bf   = (unsigned short*)p; p += (size_t)NTOT*KP*2;        // 2.6 MB
    float*          xjT    = (float*)p;          p += (size_t)KP*NTOT*4;        // 5.2 MB
    unsigned short* m_bf   = (unsigned short*)p; p += (size_t)NTOT*KP*2;
    unsigned short* v1_bf  = (unsigned short*)p; p += (size_t)NTOT*KP*2;
    float*          pooled = (float*)p;          p += (size_t)BB*HID*4;

    prep_edges<<<NEDGE/256, 256, 0, stream>>>(pos, rbf_bf, cwb);
    pack_w2<<<dim3(19, 8, NL), 256, 0, stream>>>(mw2, w2g);
    dim3 tg(10, 10, NL);
    transpose_w<<<tg, 256, 0, stream>>>(l1w, wtl1);
    transpose_w<<<tg, 256, 0, stream>>>(l2w, wtl2);
    transpose_w<<<tg, 256, 0, stream>>>(lw,  wtl);
    transpose_w1<<<NL*KP, 64, 0, stream>>>(mw1, w1t);
    gather_h<<<NTOT, 256, 0, stream>>>(z, emb, h, h_bf);

    dim3 gg(NTOT/64, KP/64);
    for (int l = 0; l < NL; l++) {
        const float* b1l  = mb1 + (size_t)l*HID;
        const float* b2l  = mb2 + (size_t)l*HID;
        const float* l2bl = l2b + (size_t)l*HID;
        const float* lbl  = lb  + (size_t)l*HID;

        // xjT = (h @ lin1_w)^T  (fp32 transposed out only)
        gemm_bf<0,0><<<gg, 256, 0, stream>>>(h_bf, wtl1 + (size_t)l*KP*KP,
                                             nullptr, nullptr, nullptr, xjT, nullptr, NTOT);
        // fused filter-net + message -> m_bf
        edge_mfma<<<NTOT/2, 256, 0, stream>>>(rbf_bf, cwb, xjT,
                                              w1t + (size_t)l*KP*64, b1l,
                                              w2g + (size_t)l*W2G_L, b2l, m_bf);
        // v1 = ssp(m @ lin2_w + lin2_b) (bf16 out only)
        gemm_bf<1,0><<<gg, 256, 0, stream>>>(m_bf, wtl2 + (size_t)l*KP*KP,
                                             l2bl, nullptr, nullptr, nullptr, v1_bf, NTOT);
        // h = h + v1 @ lin_w + lin_b (fp32 + bf16 out)
        gemm_bf<0,1><<<gg, 256, 0, stream>>>(v1_bf, wtl + (size_t)l*KP*KP,
                                             lbl, h, h, nullptr, h_bf, NTOT);
    }

    pool_mean<<<BB, 256, 0, stream>>>(h, pooled);
    gemm64<0,0><<<dim3(1, 10), 256, 0, stream>>>(pooled, pw, pb, nullptr,
                                                 (float*)d_out, BB, HID, HID);
}